// Round 1
// baseline (1353.406 us; speedup 1.0000x reference)
//
#include <hip/hip_runtime.h>
#include <math.h>

// ---------------------------------------------------------------------------
// DilatedResidualBlock baseline (f32, no MFMA).
// N=50000 nodes, K=16 edges/node (dst = e>>4, contiguous segments), D_IN=128,
// D_OUT=256, C1=64, C2=128.
// ---------------------------------------------------------------------------

__device__ __forceinline__ float lrelu_f(float v) { return v >= 0.f ? v : 0.2f * v; }

// ---------------- generic linear: out[n,DOUT] = in[n,DIN] @ w + b ----------
template<int DIN, int DOUT, int TM>
__global__ void lin_kernel(const float* __restrict__ in, const float* __restrict__ w,
                           const float* __restrict__ b, float* __restrict__ out, int n)
{
    constexpr int CT = DOUT < 256 ? DOUT : 256;   // channel-threads
    constexpr int RG = 256 / CT;                  // row groups per block
    constexpr int ROWS = TM * RG;
    __shared__ float xtile[ROWS][DIN];
    const int row0 = blockIdx.x * ROWS;
    for (int idx = threadIdx.x; idx < ROWS * DIN; idx += 256) {
        int r = idx / DIN, j = idx - r * DIN;
        int rr = row0 + r;
        xtile[r][j] = (rr < n) ? in[(size_t)rr * DIN + j] : 0.f;
    }
    __syncthreads();
    const int c  = threadIdx.x % CT;
    const int rg = threadIdx.x / CT;
    float acc[TM];
    const float bv = b[c];
#pragma unroll
    for (int t = 0; t < TM; t++) acc[t] = bv;
    for (int j = 0; j < DIN; j++) {
        float wv = w[(size_t)j * DOUT + c];
#pragma unroll
        for (int t = 0; t < TM; t++) acc[t] = fmaf(xtile[rg * TM + t][j], wv, acc[t]);
    }
#pragma unroll
    for (int t = 0; t < TM; t++) {
        int rr = row0 + rg * TM + t;
        if (rr < n) out[(size_t)rr * DOUT + c] = acc[t];
    }
}

// ---------------- column stats (sum, sumsq) over n rows --------------------
template<int C>
__global__ void colstats_kernel(const float* __restrict__ in, int n, double* __restrict__ st)
{
    constexpr int RG = 256 / C;
    const int c  = threadIdx.x % C;
    const int rg = threadIdx.x / C;
    float s = 0.f, s2 = 0.f;
    for (int r = blockIdx.x * RG + rg; r < n; r += gridDim.x * RG) {
        float v = in[(size_t)r * C + c];
        s += v;
        s2 = fmaf(v, v, s2);
    }
    __shared__ float ls[256], ls2[256];
    ls[threadIdx.x] = s; ls2[threadIdx.x] = s2;
    __syncthreads();
    if (rg == 0) {
#pragma unroll
        for (int g = 1; g < RG; g++) { s += ls[g * C + c]; s2 += ls2[g * C + c]; }
        atomicAdd(&st[c], (double)s);
        atomicAdd(&st[C + c], (double)s2);
    }
}

// ------------- stats of enc linear output (recomputed from rel) ------------
template<int CH>
__global__ void enc_stats_kernel(const float* __restrict__ rel, const float* __restrict__ ew,
                                 const float* __restrict__ eb, int E, double* __restrict__ st)
{
    constexpr int RG = 256 / CH;
    const int c  = threadIdx.x % CH;
    const int rg = threadIdx.x / CH;
    float wv[8];
#pragma unroll
    for (int j = 0; j < 8; j++) wv[j] = ew[j * CH + c];
    const float bv = eb[c];
    float s = 0.f, s2 = 0.f;
    for (int e = blockIdx.x * RG + rg; e < E; e += gridDim.x * RG) {
        float t = bv;
#pragma unroll
        for (int j = 0; j < 8; j++) t = fmaf(rel[(size_t)e * 8 + j], wv[j], t);
        s += t;
        s2 = fmaf(t, t, s2);
    }
    __shared__ float ls[256], ls2[256];
    ls[threadIdx.x] = s; ls2[threadIdx.x] = s2;
    __syncthreads();
    if (rg == 0) {
#pragma unroll
        for (int g = 1; g < RG; g++) { s += ls[g * CH + c]; s2 += ls2[g * CH + c]; }
        atomicAdd(&st[c], (double)s);
        atomicAdd(&st[CH + c], (double)s2);
    }
}

// ------------- finalize BN: (sum,sumsq) -> affine a,c ----------------------
__global__ void finalize_bn_kernel(const double* __restrict__ st, const float* __restrict__ g,
                                   const float* __restrict__ bt, int C, float n,
                                   float* __restrict__ ac)
{
    int c = threadIdx.x;
    if (c < C) {
        double m = st[c] / (double)n;
        double v = st[C + c] / (double)n - m * m;
        float rstd = (float)(1.0 / sqrt(v + 1e-6));
        float a = rstd * g[c];
        ac[c] = a;
        ac[C + c] = fmaf(-(float)m, a, bt[c]);
    }
}

// ------------- apply BN affine (+optional LeakyReLU), in-place -------------
template<bool ACT>
__global__ void bn_apply_kernel(float* __restrict__ buf, const float* __restrict__ ac,
                                int cmask, int C, size_t total)
{
    size_t i = (size_t)blockIdx.x * blockDim.x + threadIdx.x;
    size_t stride = (size_t)gridDim.x * blockDim.x;
    for (; i < total; i += stride) {
        int c = (int)i & cmask;
        float v = fmaf(buf[i], ac[c], ac[C + c]);
        buf[i] = ACT ? lrelu_f(v) : v;
    }
}

// ------------- darboux edge features [E,8] ---------------------------------
__global__ void edge_rel_kernel(const int* __restrict__ src, const float* __restrict__ pos,
                                const float* __restrict__ nrm, float* __restrict__ rel, int E)
{
    int e = blockIdx.x * blockDim.x + threadIdx.x;
    if (e >= E) return;
    const int d = e >> 4;       // dst node (contiguous segments of 16)
    const int s = src[e];
    const float pix = pos[3 * d], piy = pos[3 * d + 1], piz = pos[3 * d + 2];
    const float pjx = pos[3 * s], pjy = pos[3 * s + 1], pjz = pos[3 * s + 2];
    const float nix = nrm[3 * d], niy = nrm[3 * d + 1], niz = nrm[3 * d + 2];
    const float njx = nrm[3 * s], njy = nrm[3 * s + 1], njz = nrm[3 * s + 2];
    const float dx = pjx - pix, dy = pjy - piy, dz = pjz - piz;
    const float dist = sqrtf(dx * dx + dy * dy + dz * dz);
    const float lni = sqrtf(nix * nix + niy * niy + niz * niz);
    const float lnj = sqrtf(njx * njx + njy * njy + njz * njz);
    // uq = d x ni ; vq = uq x ni
    const float uqx = dy * niz - dz * niy, uqy = dz * nix - dx * niz, uqz = dx * niy - dy * nix;
    const float vqx = uqy * niz - uqz * niy, vqy = uqz * nix - uqx * niz, vqz = uqx * niy - uqy * nix;
    // uk = d x nj ; vk = uk x nj
    const float ukx = dy * njz - dz * njy, uky = dz * njx - dx * njz, ukz = dx * njy - dy * njx;
    const float vkx = uky * njz - ukz * njy, vky = ukz * njx - ukx * njz, vkz = ukx * njy - uky * njx;
    const float luq = sqrtf(uqx * uqx + uqy * uqy + uqz * uqz);
    const float lvq = sqrtf(vqx * vqx + vqy * vqy + vqz * vqz);
    const float luk = sqrtf(ukx * ukx + uky * uky + ukz * ukz);
    const float lvk = sqrtf(vkx * vkx + vky * vky + vkz * vkz);
    const float eps = 1e-10f;
    float* r = rel + (size_t)e * 8;
    r[0] = dist;
    r[1] = (dx * nix + dy * niy + dz * niz) / (dist * lni + eps);
    r[2] = (dx * njx + dy * njy + dz * njz) / (dist * lnj + eps);
    r[3] = (nix * njx + niy * njy + niz * njz) / (lni * lnj + eps);
    r[4] = (uqx * ukx + uqy * uky + uqz * ukz) / (luq * luk + eps);
    r[5] = (vqx * vkx + vqy * vky + vqz * vkz) / (lvq * lvk + eps);
    r[6] = (uqx * vkx + uqy * vky + uqz * vkz) / (luq * lvk + eps);
    r[7] = (vqx * ukx + vqy * uky + vqz * ukz) / (lvq * luk + eps);
}

// ------------- fused LFA: build lf, att GEMM, seg-softmax, agg, post-linear
// one wave (64 threads) per destination node
template<int C>
__global__ void lfa_kernel(const float* __restrict__ hprev,   // [n, C/2]
                           const float* __restrict__ rel,     // [E, 8]
                           const int* __restrict__ src,
                           const float* __restrict__ ew,      // [8, C/2]
                           const float* __restrict__ eb,      // [C/2]
                           const float* __restrict__ encac,   // [2*(C/2)]
                           const float* __restrict__ attw,    // [C, C]
                           const float* __restrict__ postw,   // [C, C]
                           const float* __restrict__ postb,   // [C]
                           float* __restrict__ out, int n)    // [n, C] pre-BN
{
    constexpr int HC  = C / 2;
    constexpr int CPT = C / 16;       // channels per thread in att phase
    constexpr int LFP = C + 4;        // padded row (divisible by 4 -> 16B aligned rows)
    __shared__ float lf[16][LFP];
    __shared__ float aggL[C];
    const int i   = blockIdx.x;
    const int tid = threadIdx.x;
    const int e0  = i * 16;

    // ---- build lf[16][C] = concat(hprev[src], lse) ----
    for (int k = 0; k < 16; k++) {
        const int e = e0 + k;
        const int s = src[e];
        for (int ch = tid; ch < C; ch += 64) {
            float v;
            if (ch < HC) {
                v = hprev[(size_t)s * HC + ch];
            } else {
                const int cc = ch - HC;
                float t = eb[cc];
#pragma unroll
                for (int j = 0; j < 8; j++)
                    t = fmaf(rel[(size_t)e * 8 + j], ew[j * HC + cc], t);
                t = fmaf(t, encac[cc], encac[HC + cc]);
                v = lrelu_f(t);
            }
            lf[k][ch] = v;
        }
    }
    __syncthreads();

    // ---- att = lf @ attw : thread (kg,cg) owns k in [4kg,4kg+4), ch in [cg*CPT, ...) ----
    const int kg  = tid >> 4;
    const int cg  = tid & 15;
    const int ch0 = cg * CPT;
    float att[4][CPT];
#pragma unroll
    for (int kk = 0; kk < 4; kk++)
#pragma unroll
        for (int q = 0; q < CPT; q++) att[kk][q] = 0.f;

    for (int j = 0; j < C; j += 4) {
        float4 lfv[4];
#pragma unroll
        for (int kk = 0; kk < 4; kk++)
            lfv[kk] = *reinterpret_cast<const float4*>(&lf[kg * 4 + kk][j]);
#pragma unroll
        for (int jj = 0; jj < 4; jj++) {
            const float* awrow = attw + (size_t)(j + jj) * C + ch0;
#pragma unroll
            for (int q4 = 0; q4 < CPT / 4; q4++) {
                float4 wv = *reinterpret_cast<const float4*>(awrow + q4 * 4);
#pragma unroll
                for (int kk = 0; kk < 4; kk++) {
                    const float lv = reinterpret_cast<const float*>(&lfv[kk])[jj];
                    att[kk][q4 * 4 + 0] = fmaf(lv, wv.x, att[kk][q4 * 4 + 0]);
                    att[kk][q4 * 4 + 1] = fmaf(lv, wv.y, att[kk][q4 * 4 + 1]);
                    att[kk][q4 * 4 + 2] = fmaf(lv, wv.z, att[kk][q4 * 4 + 2]);
                    att[kk][q4 * 4 + 3] = fmaf(lv, wv.w, att[kk][q4 * 4 + 3]);
                }
            }
        }
    }

    // ---- segment softmax over the 16 edges (per channel) ----
    float inv[CPT], mx[CPT];
#pragma unroll
    for (int q = 0; q < CPT; q++) {
        float m = att[0][q];
#pragma unroll
        for (int kk = 1; kk < 4; kk++) m = fmaxf(m, att[kk][q]);
        m = fmaxf(m, __shfl_xor(m, 16));
        m = fmaxf(m, __shfl_xor(m, 32));
        mx[q] = m;
    }
#pragma unroll
    for (int q = 0; q < CPT; q++) {
        float s = 0.f;
#pragma unroll
        for (int kk = 0; kk < 4; kk++) {
            att[kk][q] = __expf(att[kk][q] - mx[q]);
            s += att[kk][q];
        }
        s += __shfl_xor(s, 16);
        s += __shfl_xor(s, 32);
        inv[q] = 1.f / (s + 1e-16f);
    }

    // ---- agg = sum_k score * lf ----
    float ag[CPT];
#pragma unroll
    for (int q = 0; q < CPT; q++) ag[q] = 0.f;
#pragma unroll
    for (int kk = 0; kk < 4; kk++) {
#pragma unroll
        for (int q = 0; q < CPT; q++) {
            float lfval = lf[kg * 4 + kk][ch0 + q];
            ag[q] = fmaf(att[kk][q] * inv[q], lfval, ag[q]);
        }
    }
#pragma unroll
    for (int q = 0; q < CPT; q++) {
        ag[q] += __shfl_xor(ag[q], 16);
        ag[q] += __shfl_xor(ag[q], 32);
    }
    if (kg == 0) {
#pragma unroll
        for (int q = 0; q < CPT; q++) aggL[ch0 + q] = ag[q];
    }
    __syncthreads();

    // ---- post linear: out = agg @ postw + postb (pre-BN) ----
    for (int oc = tid; oc < C; oc += 64) {
        float p = postb[oc];
        for (int j = 0; j < C; j++) p = fmaf(aggL[j], postw[(size_t)j * C + oc], p);
        out[(size_t)i * C + oc] = p;
    }
}

// ------------- final: out = lrelu(BN(mlp2) + BN(shortcut)), in-place on d_out
__global__ void final_kernel(float* __restrict__ h2, const float* __restrict__ xs,
                             const float* __restrict__ ac2, const float* __restrict__ acs,
                             size_t total)
{
    size_t i = (size_t)blockIdx.x * blockDim.x + threadIdx.x;
    size_t stride = (size_t)gridDim.x * blockDim.x;
    for (; i < total; i += stride) {
        int c = (int)i & 255;
        float v = fmaf(h2[i], ac2[c], ac2[256 + c]) + fmaf(xs[i], acs[c], acs[256 + c]);
        h2[i] = lrelu_f(v);
    }
}

// ---------------------------------------------------------------------------
extern "C" void kernel_launch(void* const* d_in, const int* in_sizes, int n_in,
                              void* d_out, int out_size, void* d_ws, size_t ws_size,
                              hipStream_t stream)
{
    const float* x       = (const float*)d_in[0];
    const float* pos     = (const float*)d_in[1];
    const float* normals = (const float*)d_in[3];
    const int*   eidx    = (const int*)d_in[4];

    const float* mlp1_w = (const float*)d_in[5];
    const float* mlp1_b = (const float*)d_in[6];
    const float* mlp1_g = (const float*)d_in[7];
    const float* mlp1_bt= (const float*)d_in[8];
    const float* sc_w   = (const float*)d_in[9];
    const float* sc_b   = (const float*)d_in[10];
    const float* sc_g   = (const float*)d_in[11];
    const float* sc_bt  = (const float*)d_in[12];
    const float* mlp2_w = (const float*)d_in[13];
    const float* mlp2_b = (const float*)d_in[14];
    const float* mlp2_g = (const float*)d_in[15];
    const float* mlp2_bt= (const float*)d_in[16];
    const float* enc1_w = (const float*)d_in[17];
    const float* enc1_b = (const float*)d_in[18];
    const float* enc1_g = (const float*)d_in[19];
    const float* enc1_bt= (const float*)d_in[20];
    const float* att1_w = (const float*)d_in[21];
    const float* post1_w = (const float*)d_in[22];
    const float* post1_b = (const float*)d_in[23];
    const float* post1_g = (const float*)d_in[24];
    const float* post1_bt= (const float*)d_in[25];
    const float* enc2_w = (const float*)d_in[26];
    const float* enc2_b = (const float*)d_in[27];
    const float* enc2_g = (const float*)d_in[28];
    const float* enc2_bt= (const float*)d_in[29];
    const float* att2_w = (const float*)d_in[30];
    const float* post2_w = (const float*)d_in[31];
    const float* post2_b = (const float*)d_in[32];
    const float* post2_g = (const float*)d_in[33];
    const float* post2_bt= (const float*)d_in[34];

    float* out = (float*)d_out;

    const int n = in_sizes[0] / 128;     // 50000
    const int E = in_sizes[4] / 2;       // 800000
    const int* srcArr = eidx;            // row 0 of edge_index

    // ---- workspace layout ----
    char* base = (char*)d_ws;
    double* stats  = (double*)base;                       // 4096 doubles (32 KB)
    float*  affine = (float*)(base + 32768);              // 4096 floats (16 KB)
    float*  rel = (float*)(base + 49152);                 // E*8
    float*  xs  = rel + (size_t)E * 8;                    // n*256 (shortcut pre-BN)
    float*  h1  = xs  + (size_t)n * 256;                  // n*32
    float*  hA  = h1  + (size_t)n * 32;                   // n*64
    float*  hB  = hA  + (size_t)n * 64;                   // n*128

    // stats/affine offsets (elements), 2*C per layer
    const int OF_MLP1 = 0, OF_ENC1 = 64, OF_POST1 = 128, OF_ENC2 = 256,
              OF_POST2 = 384, OF_SC = 640, OF_MLP2 = 1152;

    hipMemsetAsync(stats, 0, 32768, stream);

    // shortcut & mlp1 linears
    lin_kernel<128, 256, 8><<<(n + 7) / 8, 256, 0, stream>>>(x, sc_w, sc_b, xs, n);
    lin_kernel<128, 32, 8><<<(n + 63) / 64, 256, 0, stream>>>(x, mlp1_w, mlp1_b, h1, n);

    // mlp1 BN
    colstats_kernel<32><<<512, 256, 0, stream>>>(h1, n, stats + OF_MLP1);
    finalize_bn_kernel<<<1, 256, 0, stream>>>(stats + OF_MLP1, mlp1_g, mlp1_bt, 32, (float)n, affine + OF_MLP1);
    bn_apply_kernel<true><<<2048, 256, 0, stream>>>(h1, affine + OF_MLP1, 31, 32, (size_t)n * 32);

    // darboux features
    edge_rel_kernel<<<(E + 255) / 256, 256, 0, stream>>>(srcArr, pos, normals, rel, E);

    // enc1 BN stats (recompute t from rel)
    enc_stats_kernel<32><<<1024, 256, 0, stream>>>(rel, enc1_w, enc1_b, E, stats + OF_ENC1);
    finalize_bn_kernel<<<1, 256, 0, stream>>>(stats + OF_ENC1, enc1_g, enc1_bt, 32, (float)E, affine + OF_ENC1);

    // LFA 1 (C=64)
    lfa_kernel<64><<<n, 64, 0, stream>>>(h1, rel, srcArr, enc1_w, enc1_b, affine + OF_ENC1,
                                         att1_w, post1_w, post1_b, hA, n);
    colstats_kernel<64><<<512, 256, 0, stream>>>(hA, n, stats + OF_POST1);
    finalize_bn_kernel<<<1, 256, 0, stream>>>(stats + OF_POST1, post1_g, post1_bt, 64, (float)n, affine + OF_POST1);
    bn_apply_kernel<true><<<2048, 256, 0, stream>>>(hA, affine + OF_POST1, 63, 64, (size_t)n * 64);

    // enc2 BN stats
    enc_stats_kernel<64><<<1024, 256, 0, stream>>>(rel, enc2_w, enc2_b, E, stats + OF_ENC2);
    finalize_bn_kernel<<<1, 256, 0, stream>>>(stats + OF_ENC2, enc2_g, enc2_bt, 64, (float)E, affine + OF_ENC2);

    // LFA 2 (C=128)
    lfa_kernel<128><<<n, 64, 0, stream>>>(hA, rel, srcArr, enc2_w, enc2_b, affine + OF_ENC2,
                                          att2_w, post2_w, post2_b, hB, n);
    colstats_kernel<128><<<512, 256, 0, stream>>>(hB, n, stats + OF_POST2);
    finalize_bn_kernel<<<1, 256, 0, stream>>>(stats + OF_POST2, post2_g, post2_bt, 128, (float)n, affine + OF_POST2);
    bn_apply_kernel<true><<<2048, 256, 0, stream>>>(hB, affine + OF_POST2, 127, 128, (size_t)n * 128);

    // mlp2 linear -> d_out (pre-BN)
    lin_kernel<128, 256, 8><<<(n + 7) / 8, 256, 0, stream>>>(hB, mlp2_w, mlp2_b, out, n);

    // mlp2 + shortcut BN stats
    colstats_kernel<256><<<512, 256, 0, stream>>>(out, n, stats + OF_MLP2);
    colstats_kernel<256><<<512, 256, 0, stream>>>(xs, n, stats + OF_SC);
    finalize_bn_kernel<<<1, 256, 0, stream>>>(stats + OF_MLP2, mlp2_g, mlp2_bt, 256, (float)n, affine + OF_MLP2);
    finalize_bn_kernel<<<1, 256, 0, stream>>>(stats + OF_SC, sc_g, sc_bt, 256, (float)n, affine + OF_SC);

    // final combine (in-place on d_out)
    final_kernel<<<4096, 256, 0, stream>>>(out, xs, affine + OF_MLP2, affine + OF_SC, (size_t)n * 256);
}

// Round 2
// 711.020 us; speedup vs baseline: 1.9035x; 1.9035x over previous
//
#include <hip/hip_runtime.h>
#include <hip/hip_bf16.h>
#include <math.h>

// ---------------------------------------------------------------------------
// DilatedResidualBlock: round 1 — MFMA-based LFA kernels.
// N=50000 nodes, K=16 edges/node (dst = e>>4 contiguous), D_IN=128, D_OUT=256.
// ---------------------------------------------------------------------------

typedef __attribute__((ext_vector_type(8))) short short8;
typedef __attribute__((ext_vector_type(4))) float floatx4;

__device__ __forceinline__ float lrelu_f(float v) { return v >= 0.f ? v : 0.2f * v; }

__device__ __forceinline__ ushort f2bf(float f) {
    union { __hip_bfloat16 h; ushort u; } cv;
    cv.h = __float2bfloat16(f);
    return cv.u;
}
__device__ __forceinline__ float bf2f(ushort u) {
    union { ushort u; __hip_bfloat16 h; } cv;
    cv.u = u;
    return __bfloat162float(cv.h);
}

// ---------------- generic linear: out[n,DOUT] = in[n,DIN] @ w + b ----------
template<int DIN, int DOUT, int TM>
__global__ void lin_kernel(const float* __restrict__ in, const float* __restrict__ w,
                           const float* __restrict__ b, float* __restrict__ out, int n)
{
    constexpr int CT = DOUT < 256 ? DOUT : 256;
    constexpr int RG = 256 / CT;
    constexpr int ROWS = TM * RG;
    __shared__ float xtile[ROWS][DIN];
    const int row0 = blockIdx.x * ROWS;
    for (int idx = threadIdx.x; idx < ROWS * DIN; idx += 256) {
        int r = idx / DIN, j = idx - r * DIN;
        int rr = row0 + r;
        xtile[r][j] = (rr < n) ? in[(size_t)rr * DIN + j] : 0.f;
    }
    __syncthreads();
    const int c  = threadIdx.x % CT;
    const int rg = threadIdx.x / CT;
    float acc[TM];
    const float bv = b[c];
#pragma unroll
    for (int t = 0; t < TM; t++) acc[t] = bv;
    for (int j = 0; j < DIN; j++) {
        float wv = w[(size_t)j * DOUT + c];
#pragma unroll
        for (int t = 0; t < TM; t++) acc[t] = fmaf(xtile[rg * TM + t][j], wv, acc[t]);
    }
#pragma unroll
    for (int t = 0; t < TM; t++) {
        int rr = row0 + rg * TM + t;
        if (rr < n) out[(size_t)rr * DOUT + c] = acc[t];
    }
}

// ---------------- column stats (sum, sumsq) over n rows --------------------
template<int C>
__global__ void colstats_kernel(const float* __restrict__ in, int n, double* __restrict__ st)
{
    constexpr int RG = 256 / C;
    const int c  = threadIdx.x % C;
    const int rg = threadIdx.x / C;
    float s = 0.f, s2 = 0.f;
    for (int r = blockIdx.x * RG + rg; r < n; r += gridDim.x * RG) {
        float v = in[(size_t)r * C + c];
        s += v;
        s2 = fmaf(v, v, s2);
    }
    __shared__ float ls[256], ls2[256];
    ls[threadIdx.x] = s; ls2[threadIdx.x] = s2;
    __syncthreads();
    if (rg == 0) {
#pragma unroll
        for (int g = 1; g < RG; g++) { s += ls[g * C + c]; s2 += ls2[g * C + c]; }
        atomicAdd(&st[c], (double)s);
        atomicAdd(&st[C + c], (double)s2);
    }
}

// ------------- stats of enc linear output (recomputed from rel) ------------
template<int CH>
__global__ void enc_stats_kernel(const float* __restrict__ rel, const float* __restrict__ ew,
                                 const float* __restrict__ eb, int E, double* __restrict__ st)
{
    constexpr int RG = 256 / CH;
    const int c  = threadIdx.x % CH;
    const int rg = threadIdx.x / CH;
    float wv[8];
#pragma unroll
    for (int j = 0; j < 8; j++) wv[j] = ew[j * CH + c];
    const float bv = eb[c];
    float s = 0.f, s2 = 0.f;
    for (int e = blockIdx.x * RG + rg; e < E; e += gridDim.x * RG) {
        float t = bv;
#pragma unroll
        for (int j = 0; j < 8; j++) t = fmaf(rel[(size_t)e * 8 + j], wv[j], t);
        s += t;
        s2 = fmaf(t, t, s2);
    }
    __shared__ float ls[256], ls2[256];
    ls[threadIdx.x] = s; ls2[threadIdx.x] = s2;
    __syncthreads();
    if (rg == 0) {
#pragma unroll
        for (int g = 1; g < RG; g++) { s += ls[g * CH + c]; s2 += ls2[g * CH + c]; }
        atomicAdd(&st[c], (double)s);
        atomicAdd(&st[CH + c], (double)s2);
    }
}

// ------------- finalize BN: (sum,sumsq) -> affine a,c ----------------------
__global__ void finalize_bn_kernel(const double* __restrict__ st, const float* __restrict__ g,
                                   const float* __restrict__ bt, int C, float n,
                                   float* __restrict__ ac)
{
    int c = threadIdx.x;
    if (c < C) {
        double m = st[c] / (double)n;
        double v = st[C + c] / (double)n - m * m;
        float rstd = (float)(1.0 / sqrt(v + 1e-6));
        float a = rstd * g[c];
        ac[c] = a;
        ac[C + c] = fmaf(-(float)m, a, bt[c]);
    }
}

// ------------- apply BN affine (+optional LeakyReLU), in-place -------------
template<bool ACT>
__global__ void bn_apply_kernel(float* __restrict__ buf, const float* __restrict__ ac,
                                int cmask, int C, size_t total)
{
    size_t i = (size_t)blockIdx.x * blockDim.x + threadIdx.x;
    size_t stride = (size_t)gridDim.x * blockDim.x;
    for (; i < total; i += stride) {
        int c = (int)i & cmask;
        float v = fmaf(buf[i], ac[c], ac[C + c]);
        buf[i] = ACT ? lrelu_f(v) : v;
    }
}

// ------------- darboux edge features [E,8] ---------------------------------
__global__ void edge_rel_kernel(const int* __restrict__ src, const float* __restrict__ pos,
                                const float* __restrict__ nrm, float* __restrict__ rel, int E)
{
    int e = blockIdx.x * blockDim.x + threadIdx.x;
    if (e >= E) return;
    const int d = e >> 4;
    const int s = src[e];
    const float pix = pos[3 * d], piy = pos[3 * d + 1], piz = pos[3 * d + 2];
    const float pjx = pos[3 * s], pjy = pos[3 * s + 1], pjz = pos[3 * s + 2];
    const float nix = nrm[3 * d], niy = nrm[3 * d + 1], niz = nrm[3 * d + 2];
    const float njx = nrm[3 * s], njy = nrm[3 * s + 1], njz = nrm[3 * s + 2];
    const float dx = pjx - pix, dy = pjy - piy, dz = pjz - piz;
    const float dist = sqrtf(dx * dx + dy * dy + dz * dz);
    const float lni = sqrtf(nix * nix + niy * niy + niz * niz);
    const float lnj = sqrtf(njx * njx + njy * njy + njz * njz);
    const float uqx = dy * niz - dz * niy, uqy = dz * nix - dx * niz, uqz = dx * niy - dy * nix;
    const float vqx = uqy * niz - uqz * niy, vqy = uqz * nix - uqx * niz, vqz = uqx * niy - uqy * nix;
    const float ukx = dy * njz - dz * njy, uky = dz * njx - dx * njz, ukz = dx * njy - dy * njx;
    const float vkx = uky * njz - ukz * njy, vky = ukz * njx - ukx * njz, vkz = ukx * njy - uky * njx;
    const float luq = sqrtf(uqx * uqx + uqy * uqy + uqz * uqz);
    const float lvq = sqrtf(vqx * vqx + vqy * vqy + vqz * vqz);
    const float luk = sqrtf(ukx * ukx + uky * uky + ukz * ukz);
    const float lvk = sqrtf(vkx * vkx + vky * vky + vkz * vkz);
    const float eps = 1e-10f;
    float* r = rel + (size_t)e * 8;
    r[0] = dist;
    r[1] = (dx * nix + dy * niy + dz * niz) / (dist * lni + eps);
    r[2] = (dx * njx + dy * njy + dz * njz) / (dist * lnj + eps);
    r[3] = (nix * njx + niy * njy + niz * njz) / (lni * lnj + eps);
    r[4] = (uqx * ukx + uqy * uky + uqz * ukz) / (luq * luk + eps);
    r[5] = (vqx * vkx + vqy * vky + vqz * vkz) / (lvq * lvk + eps);
    r[6] = (uqx * vkx + uqy * vky + uqz * vkz) / (luq * lvk + eps);
    r[7] = (vqx * ukx + vqy * uky + vqz * ukz) / (lvq * luk + eps);
}

// ---------------------------------------------------------------------------
// MFMA LFA: block = 256 thr = 4 waves, processes 16 nodes (batch).
// Per node: gather+enc build lf[16][C] bf16 (XOR-swizzled), per-wave att MFMA
// (B frags in VGPRs), shfl softmax over 16 edges, agg -> agg[16][C] bf16.
// Then one batched post-GEMM via MFMA writes pre-BN out rows.
// ---------------------------------------------------------------------------
template<int C>
__global__ __launch_bounds__(256)
void lfa_mfma_kernel(const float* __restrict__ hprev,   // [n, C/2]
                     const float* __restrict__ rel,     // [E, 8]
                     const int* __restrict__ src,
                     const float* __restrict__ ew,      // [8, C/2]
                     const float* __restrict__ eb,      // [C/2]
                     const float* __restrict__ encac,   // [2*(C/2)]
                     const float* __restrict__ attw,    // [C, C]
                     const float* __restrict__ postw,   // [C, C]
                     const float* __restrict__ postb,   // [C]
                     float* __restrict__ out, int n)    // [n, C] pre-BN
{
    constexpr int HC   = C / 2;
    constexpr int NT   = C / 16;      // n-tiles
    constexpr int NTW  = NT / 4;      // n-tiles per wave
    constexpr int KK   = C / 32;      // K-steps
    constexpr int ROWB = 2 * C;       // bytes per bf16 row

    __shared__ __align__(16) char lfS[16 * ROWB];
    __shared__ __align__(16) char aggS[16 * ROWB];

    const int lane  = threadIdx.x & 63;
    const int w     = threadIdx.x >> 6;
    const int grp   = lane >> 4;
    const int l15   = lane & 15;
    const int node0 = blockIdx.x << 4;

    // ---- preload B fragments (att + post) into VGPRs, bf16 ----
    short8 Batt[NTW][KK], Bpost[NTW][KK];
    float pb[NTW];
#pragma unroll
    for (int t = 0; t < NTW; t++) {
        const int c = (w * NTW + t) * 16 + l15;
        pb[t] = postb[c];
#pragma unroll
        for (int kk = 0; kk < KK; kk++) {
#pragma unroll
            for (int e = 0; e < 8; e++) {
                const int k = kk * 32 + (grp << 3) + e;
                Batt[t][kk][e] = (short)f2bf(attw[(size_t)k * C + c]);
                Bpost[t][kk][e] = (short)f2bf(postw[(size_t)k * C + c]);
            }
        }
    }

    // ---- enc constants (waves 0..HC/16-1 own one 16-channel enc tile) ----
    short8 Benc = {0, 0, 0, 0, 0, 0, 0, 0};
    float encA = 0.f, encB2 = 0.f;
    if (w < HC / 16) {
        const int cc = w * 16 + l15;
        encA  = encac[cc];
        encB2 = fmaf(encA, eb[cc], encac[HC + cc]);
        if (grp == 0) {
#pragma unroll
            for (int e = 0; e < 8; e++) Benc[e] = (short)f2bf(ew[e * HC + cc]);
        }
    }

    for (int brow = 0; brow < 16; ++brow) {
        const int node = (node0 + brow < n) ? node0 + brow : n - 1;
        const int e0 = node << 4;
        __syncthreads();   // protect lf from previous iteration's readers

        // ---- gather half: lf[:, 0:HC] = hprev[src] (bf16, swizzled) ----
        {
            const int k = threadIdx.x >> 4;      // edge row 0..15
            const int q = threadIdx.x & 15;
            const int s = src[e0 + k];
            if constexpr (C == 128) {
                const float4 hv = *reinterpret_cast<const float4*>(hprev + (size_t)s * 64 + q * 4);
                uint2 pk;
                pk.x = (uint)f2bf(hv.x) | ((uint)f2bf(hv.y) << 16);
                pk.y = (uint)f2bf(hv.z) | ((uint)f2bf(hv.w) << 16);
                const int unit = q >> 1;
                *reinterpret_cast<uint2*>(lfS + k * ROWB + (((unit) ^ (k & 7)) << 4) + (q & 1) * 8) = pk;
            } else {
                const float2 hv = *reinterpret_cast<const float2*>(hprev + (size_t)s * 32 + q * 2);
                uint pk = (uint)f2bf(hv.x) | ((uint)f2bf(hv.y) << 16);
                *reinterpret_cast<uint*>(lfS + k * ROWB + (((q >> 2) ^ (k & 7)) << 4) + (q & 3) * 4) = pk;
            }
        }

        // ---- enc half via MFMA: lse = lrelu(BN(rel @ ew)) ----
        if (w < HC / 16) {
            const float4 r0 = *reinterpret_cast<const float4*>(rel + (size_t)(e0 + l15) * 8);
            const float4 r1 = *reinterpret_cast<const float4*>(rel + (size_t)(e0 + l15) * 8 + 4);
            short8 Arel;
            Arel[0] = (short)f2bf(r0.x); Arel[1] = (short)f2bf(r0.y);
            Arel[2] = (short)f2bf(r0.z); Arel[3] = (short)f2bf(r0.w);
            Arel[4] = (short)f2bf(r1.x); Arel[5] = (short)f2bf(r1.y);
            Arel[6] = (short)f2bf(r1.z); Arel[7] = (short)f2bf(r1.w);
            floatx4 accE = {0.f, 0.f, 0.f, 0.f};
            accE = __builtin_amdgcn_mfma_f32_16x16x32_bf16(Arel, Benc, accE, 0, 0, 0);
            const int cfull = HC + w * 16 + l15;
            const int unit = cfull >> 3;
#pragma unroll
            for (int r = 0; r < 4; r++) {
                const int kedge = (grp << 2) + r;
                float t = fmaf(accE[r], encA, encB2);
                t = lrelu_f(t);
                *reinterpret_cast<ushort*>(lfS + kedge * ROWB + ((unit ^ (kedge & 7)) << 4) + (cfull & 7) * 2) = f2bf(t);
            }
        }
        __syncthreads();

        // ---- att GEMM (per wave: NTW tiles) ----
        floatx4 acc[NTW];
#pragma unroll
        for (int t = 0; t < NTW; t++) acc[t] = (floatx4){0.f, 0.f, 0.f, 0.f};
#pragma unroll
        for (int kk = 0; kk < KK; kk++) {
            const int row = l15;
            short8 a = *reinterpret_cast<const short8*>(lfS + row * ROWB + ((((kk << 2) + grp) ^ (row & 7)) << 4));
#pragma unroll
            for (int t = 0; t < NTW; t++)
                acc[t] = __builtin_amdgcn_mfma_f32_16x16x32_bf16(a, Batt[t][kk], acc[t], 0, 0, 0);
        }

        // ---- softmax over 16 edges + weighted agg per channel ----
#pragma unroll
        for (int t = 0; t < NTW; t++) {
            float m = fmaxf(fmaxf(acc[t][0], acc[t][1]), fmaxf(acc[t][2], acc[t][3]));
            m = fmaxf(m, __shfl_xor(m, 16));
            m = fmaxf(m, __shfl_xor(m, 32));
            float ev[4];
            float ssum = 0.f;
#pragma unroll
            for (int r = 0; r < 4; r++) { ev[r] = __expf(acc[t][r] - m); ssum += ev[r]; }
            ssum += __shfl_xor(ssum, 16);
            ssum += __shfl_xor(ssum, 32);
            const float inv = 1.f / (ssum + 1e-16f);
            const int c = (w * NTW + t) * 16 + l15;
            const int unit = c >> 3;
            const int sub = (c & 7) * 2;
            float av = 0.f;
#pragma unroll
            for (int r = 0; r < 4; r++) {
                const int kedge = (grp << 2) + r;
                float lfv = bf2f(*reinterpret_cast<const ushort*>(lfS + kedge * ROWB + ((unit ^ (kedge & 7)) << 4) + sub));
                av = fmaf(ev[r] * inv, lfv, av);
            }
            av += __shfl_xor(av, 16);
            av += __shfl_xor(av, 32);
            if (grp == 0)
                *reinterpret_cast<ushort*>(aggS + brow * ROWB + ((unit ^ (brow & 7)) << 4) + sub) = f2bf(av);
        }
    }
    __syncthreads();

    // ---- batched post-GEMM: out rows = agg @ postw + postb (pre-BN) ----
    floatx4 accP[NTW];
#pragma unroll
    for (int t = 0; t < NTW; t++) accP[t] = (floatx4){0.f, 0.f, 0.f, 0.f};
#pragma unroll
    for (int kk = 0; kk < KK; kk++) {
        const int row = l15;
        short8 a = *reinterpret_cast<const short8*>(aggS + row * ROWB + ((((kk << 2) + grp) ^ (row & 7)) << 4));
#pragma unroll
        for (int t = 0; t < NTW; t++)
            accP[t] = __builtin_amdgcn_mfma_f32_16x16x32_bf16(a, Bpost[t][kk], accP[t], 0, 0, 0);
    }
#pragma unroll
    for (int t = 0; t < NTW; t++) {
        const int c = (w * NTW + t) * 16 + l15;
#pragma unroll
        for (int r = 0; r < 4; r++) {
            const int brow = (grp << 2) + r;
            if (node0 + brow < n)
                out[(size_t)(node0 + brow) * C + c] = accP[t][r] + pb[t];
        }
    }
}

// ------------- final: out = lrelu(BN(mlp2) + BN(shortcut)), in-place -------
__global__ void final_kernel(float* __restrict__ h2, const float* __restrict__ xs,
                             const float* __restrict__ ac2, const float* __restrict__ acs,
                             size_t total)
{
    size_t i = (size_t)blockIdx.x * blockDim.x + threadIdx.x;
    size_t stride = (size_t)gridDim.x * blockDim.x;
    for (; i < total; i += stride) {
        int c = (int)i & 255;
        float v = fmaf(h2[i], ac2[c], ac2[256 + c]) + fmaf(xs[i], acs[c], acs[256 + c]);
        h2[i] = lrelu_f(v);
    }
}

// ---------------------------------------------------------------------------
extern "C" void kernel_launch(void* const* d_in, const int* in_sizes, int n_in,
                              void* d_out, int out_size, void* d_ws, size_t ws_size,
                              hipStream_t stream)
{
    const float* x       = (const float*)d_in[0];
    const float* pos     = (const float*)d_in[1];
    const float* normals = (const float*)d_in[3];
    const int*   eidx    = (const int*)d_in[4];

    const float* mlp1_w = (const float*)d_in[5];
    const float* mlp1_b = (const float*)d_in[6];
    const float* mlp1_g = (const float*)d_in[7];
    const float* mlp1_bt= (const float*)d_in[8];
    const float* sc_w   = (const float*)d_in[9];
    const float* sc_b   = (const float*)d_in[10];
    const float* sc_g   = (const float*)d_in[11];
    const float* sc_bt  = (const float*)d_in[12];
    const float* mlp2_w = (const float*)d_in[13];
    const float* mlp2_b = (const float*)d_in[14];
    const float* mlp2_g = (const float*)d_in[15];
    const float* mlp2_bt= (const float*)d_in[16];
    const float* enc1_w = (const float*)d_in[17];
    const float* enc1_b = (const float*)d_in[18];
    const float* enc1_g = (const float*)d_in[19];
    const float* enc1_bt= (const float*)d_in[20];
    const float* att1_w = (const float*)d_in[21];
    const float* post1_w = (const float*)d_in[22];
    const float* post1_b = (const float*)d_in[23];
    const float* post1_g = (const float*)d_in[24];
    const float* post1_bt= (const float*)d_in[25];
    const float* enc2_w = (const float*)d_in[26];
    const float* enc2_b = (const float*)d_in[27];
    const float* enc2_g = (const float*)d_in[28];
    const float* enc2_bt= (const float*)d_in[29];
    const float* att2_w = (const float*)d_in[30];
    const float* post2_w = (const float*)d_in[31];
    const float* post2_b = (const float*)d_in[32];
    const float* post2_g = (const float*)d_in[33];
    const float* post2_bt= (const float*)d_in[34];

    float* out = (float*)d_out;

    const int n = in_sizes[0] / 128;     // 50000
    const int E = in_sizes[4] / 2;       // 800000
    const int* srcArr = eidx;            // row 0 of edge_index

    // ---- workspace layout ----
    char* base = (char*)d_ws;
    double* stats  = (double*)base;                       // 4096 doubles (32 KB)
    float*  affine = (float*)(base + 32768);              // 4096 floats (16 KB)
    float*  rel = (float*)(base + 49152);                 // E*8
    float*  xs  = rel + (size_t)E * 8;                    // n*256 (shortcut pre-BN)
    float*  h1  = xs  + (size_t)n * 256;                  // n*32
    float*  hA  = h1  + (size_t)n * 32;                   // n*64
    float*  hB  = hA  + (size_t)n * 64;                   // n*128

    const int OF_MLP1 = 0, OF_ENC1 = 64, OF_POST1 = 128, OF_ENC2 = 256,
              OF_POST2 = 384, OF_SC = 640, OF_MLP2 = 1152;

    hipMemsetAsync(stats, 0, 32768, stream);

    // shortcut & mlp1 linears
    lin_kernel<128, 256, 8><<<(n + 7) / 8, 256, 0, stream>>>(x, sc_w, sc_b, xs, n);
    lin_kernel<128, 32, 8><<<(n + 63) / 64, 256, 0, stream>>>(x, mlp1_w, mlp1_b, h1, n);

    // mlp1 BN
    colstats_kernel<32><<<512, 256, 0, stream>>>(h1, n, stats + OF_MLP1);
    finalize_bn_kernel<<<1, 256, 0, stream>>>(stats + OF_MLP1, mlp1_g, mlp1_bt, 32, (float)n, affine + OF_MLP1);
    bn_apply_kernel<true><<<2048, 256, 0, stream>>>(h1, affine + OF_MLP1, 31, 32, (size_t)n * 32);

    // darboux features
    edge_rel_kernel<<<(E + 255) / 256, 256, 0, stream>>>(srcArr, pos, normals, rel, E);

    // enc1 BN stats
    enc_stats_kernel<32><<<1024, 256, 0, stream>>>(rel, enc1_w, enc1_b, E, stats + OF_ENC1);
    finalize_bn_kernel<<<1, 256, 0, stream>>>(stats + OF_ENC1, enc1_g, enc1_bt, 32, (float)E, affine + OF_ENC1);

    // LFA 1 (C=64)
    lfa_mfma_kernel<64><<<(n + 15) / 16, 256, 0, stream>>>(h1, rel, srcArr, enc1_w, enc1_b,
        affine + OF_ENC1, att1_w, post1_w, post1_b, hA, n);
    colstats_kernel<64><<<512, 256, 0, stream>>>(hA, n, stats + OF_POST1);
    finalize_bn_kernel<<<1, 256, 0, stream>>>(stats + OF_POST1, post1_g, post1_bt, 64, (float)n, affine + OF_POST1);
    bn_apply_kernel<true><<<2048, 256, 0, stream>>>(hA, affine + OF_POST1, 63, 64, (size_t)n * 64);

    // enc2 BN stats
    enc_stats_kernel<64><<<1024, 256, 0, stream>>>(rel, enc2_w, enc2_b, E, stats + OF_ENC2);
    finalize_bn_kernel<<<1, 256, 0, stream>>>(stats + OF_ENC2, enc2_g, enc2_bt, 64, (float)E, affine + OF_ENC2);

    // LFA 2 (C=128)
    lfa_mfma_kernel<128><<<(n + 15) / 16, 256, 0, stream>>>(hA, rel, srcArr, enc2_w, enc2_b,
        affine + OF_ENC2, att2_w, post2_w, post2_b, hB, n);
    colstats_kernel<128><<<512, 256, 0, stream>>>(hB, n, stats + OF_POST2);
    finalize_bn_kernel<<<1, 256, 0, stream>>>(stats + OF_POST2, post2_g, post2_bt, 128, (float)n, affine + OF_POST2);
    bn_apply_kernel<true><<<2048, 256, 0, stream>>>(hB, affine + OF_POST2, 127, 128, (size_t)n * 128);

    // mlp2 linear -> d_out (pre-BN)
    lin_kernel<128, 256, 8><<<(n + 7) / 8, 256, 0, stream>>>(hB, mlp2_w, mlp2_b, out, n);

    // mlp2 + shortcut BN stats
    colstats_kernel<256><<<512, 256, 0, stream>>>(out, n, stats + OF_MLP2);
    colstats_kernel<256><<<512, 256, 0, stream>>>(xs, n, stats + OF_SC);
    finalize_bn_kernel<<<1, 256, 0, stream>>>(stats + OF_MLP2, mlp2_g, mlp2_bt, 256, (float)n, affine + OF_MLP2);
    finalize_bn_kernel<<<1, 256, 0, stream>>>(stats + OF_SC, sc_g, sc_bt, 256, (float)n, affine + OF_SC);

    // final combine (in-place on d_out)
    final_kernel<<<4096, 256, 0, stream>>>(out, xs, affine + OF_MLP2, affine + OF_SC, (size_t)n * 256);
}

// Round 3
// 511.201 us; speedup vs baseline: 2.6475x; 1.3909x over previous
//
#include <hip/hip_runtime.h>
#include <hip/hip_bf16.h>
#include <math.h>

// ---------------------------------------------------------------------------
// DilatedResidualBlock round 2: batched-node MFMA LFA, prepped bf16 weights,
// MFMA linears, BN-apply fused into consumers.
// N=50000, K=16 (dst = e>>4 contiguous), D_IN=128, D_OUT=256, C1=64, C2=128.
// ---------------------------------------------------------------------------

typedef __attribute__((ext_vector_type(8))) short short8;
typedef __attribute__((ext_vector_type(4))) float floatx4;

__device__ __forceinline__ float lrelu_f(float v) { return v >= 0.f ? v : 0.2f * v; }

__device__ __forceinline__ ushort f2bf(float f) {
    union { __hip_bfloat16 h; ushort u; } cv;
    cv.h = __float2bfloat16(f);
    return cv.u;
}
__device__ __forceinline__ float bf2f(ushort u) {
    union { ushort u; __hip_bfloat16 h; } cv;
    cv.u = u;
    return __bfloat162float(cv.h);
}
__device__ __forceinline__ uint pack2bf(float lo, float hi) {
    return (uint)f2bf(lo) | ((uint)f2bf(hi) << 16);
}

// ---------------- weight prep: f32 [K][Cout] -> bf16 MFMA-fragment order ----
struct PrepSeg { const float* src; short* dst; int cnt; int Cout; int KK; };
struct PrepArgs { PrepSeg seg[6]; };

__global__ void wprep_kernel(PrepArgs pa)
{
    int gid = blockIdx.x * 256 + threadIdx.x;
    int base = 0;
    for (int s = 0; s < 6; s++) {
        int c = pa.seg[s].cnt;
        if (gid < base + c) {
            int fi = gid - base;
            const float* w = pa.seg[s].src;
            const int Cout = pa.seg[s].Cout, KK = pa.seg[s].KK;
            const int l15 = fi & 15, g = (fi >> 4) & 3, rest = fi >> 6;
            const int kk = rest % KK, nt = rest / KK;
            const int col = nt * 16 + l15;
            short8 v;
#pragma unroll
            for (int e = 0; e < 8; e++)
                v[e] = (short)f2bf(w[(size_t)(kk * 32 + g * 8 + e) * Cout + col]);
            *reinterpret_cast<short8*>(pa.seg[s].dst + (size_t)fi * 8) = v;
            return;
        }
        base += c;
    }
}

// ---------------- f32 linear (mlp1 only, DOUT=32) --------------------------
template<int DIN, int DOUT, int TM>
__global__ void lin_kernel(const float* __restrict__ in, const float* __restrict__ w,
                           const float* __restrict__ b, float* __restrict__ out, int n)
{
    constexpr int CT = DOUT < 256 ? DOUT : 256;
    constexpr int RG = 256 / CT;
    constexpr int ROWS = TM * RG;
    __shared__ float xtile[ROWS][DIN];
    const int row0 = blockIdx.x * ROWS;
    for (int idx = threadIdx.x; idx < ROWS * DIN; idx += 256) {
        int r = idx / DIN, j = idx - r * DIN;
        int rr = row0 + r;
        xtile[r][j] = (rr < n) ? in[(size_t)rr * DIN + j] : 0.f;
    }
    __syncthreads();
    const int c  = threadIdx.x % CT;
    const int rg = threadIdx.x / CT;
    float acc[TM];
    const float bv = b[c];
#pragma unroll
    for (int t = 0; t < TM; t++) acc[t] = bv;
    for (int j = 0; j < DIN; j++) {
        float wv = w[(size_t)j * DOUT + c];
#pragma unroll
        for (int t = 0; t < TM; t++) acc[t] = fmaf(xtile[rg * TM + t][j], wv, acc[t]);
    }
#pragma unroll
    for (int t = 0; t < TM; t++) {
        int rr = row0 + rg * TM + t;
        if (rr < n) out[(size_t)rr * DOUT + c] = acc[t];
    }
}

// ---------------- MFMA linear: [n,128] @ [128,256] + b, optional in-affine --
template<bool AFF>
__global__ __launch_bounds__(256)
void lin_mfma_kernel(const float* __restrict__ in, const float* __restrict__ aff,
                     const short* __restrict__ wp, const float* __restrict__ b,
                     float* __restrict__ out, int n)
{
    __shared__ __align__(16) char aS[64 * 256];
    const int tid = threadIdx.x;
    const int w = tid >> 6, grp = (tid >> 4) & 3, l15 = tid & 15;
    const int row0 = blockIdx.x * 64;
    {
        const int r = tid >> 2;
        const int p = tid & 3;
        const int chbase = p * 32;
        const int gr = row0 + r;
        if (gr < n) {
            const float* hrow = in + (size_t)gr * 128 + chbase;
#pragma unroll
            for (int u = 0; u < 4; u++) {
                float4 h0 = *reinterpret_cast<const float4*>(hrow + u * 8);
                float4 h1 = *reinterpret_cast<const float4*>(hrow + u * 8 + 4);
                if constexpr (AFF) {
                    const float* ar = aff + chbase + u * 8;
                    const float* cr = aff + 128 + chbase + u * 8;
                    float4 a0 = *reinterpret_cast<const float4*>(ar);
                    float4 a1 = *reinterpret_cast<const float4*>(ar + 4);
                    float4 c0 = *reinterpret_cast<const float4*>(cr);
                    float4 c1 = *reinterpret_cast<const float4*>(cr + 4);
                    h0.x = lrelu_f(fmaf(h0.x, a0.x, c0.x)); h0.y = lrelu_f(fmaf(h0.y, a0.y, c0.y));
                    h0.z = lrelu_f(fmaf(h0.z, a0.z, c0.z)); h0.w = lrelu_f(fmaf(h0.w, a0.w, c0.w));
                    h1.x = lrelu_f(fmaf(h1.x, a1.x, c1.x)); h1.y = lrelu_f(fmaf(h1.y, a1.y, c1.y));
                    h1.z = lrelu_f(fmaf(h1.z, a1.z, c1.z)); h1.w = lrelu_f(fmaf(h1.w, a1.w, c1.w));
                }
                uint4 pk;
                pk.x = pack2bf(h0.x, h0.y); pk.y = pack2bf(h0.z, h0.w);
                pk.z = pack2bf(h1.x, h1.y); pk.w = pack2bf(h1.z, h1.w);
                const int unit = (chbase >> 3) + u;
                *reinterpret_cast<uint4*>(aS + r * 256 + ((unit ^ (r & 7)) << 4)) = pk;
            }
        }
    }
    __syncthreads();

    short8 B[4][4]; float bias[4];
#pragma unroll
    for (int t = 0; t < 4; t++) {
        const int nt = w * 4 + t;
        bias[t] = b[nt * 16 + l15];
#pragma unroll
        for (int kk = 0; kk < 4; kk++)
            B[t][kk] = *reinterpret_cast<const short8*>(wp + (size_t)(((nt * 4 + kk) * 4 + grp) * 16 + l15) * 8);
    }
#pragma unroll
    for (int mt = 0; mt < 4; mt++) {
        short8 a[4];
        const int arow = mt * 16 + l15;
#pragma unroll
        for (int kk = 0; kk < 4; kk++)
            a[kk] = *reinterpret_cast<const short8*>(aS + arow * 256 + ((((kk << 2) + grp) ^ (arow & 7)) << 4));
#pragma unroll
        for (int t = 0; t < 4; t++) {
            floatx4 acc = {bias[t], bias[t], bias[t], bias[t]};
#pragma unroll
            for (int kk = 0; kk < 4; kk++)
                acc = __builtin_amdgcn_mfma_f32_16x16x32_bf16(a[kk], B[t][kk], acc, 0, 0, 0);
            const int c = (w * 4 + t) * 16 + l15;
#pragma unroll
            for (int r = 0; r < 4; r++) {
                const int grow = row0 + mt * 16 + grp * 4 + r;
                if (grow < n) out[(size_t)grow * 256 + c] = acc[r];
            }
        }
    }
}

// ---------------- column stats (sum, sumsq) --------------------------------
template<int C>
__global__ void colstats_kernel(const float* __restrict__ in, int n, double* __restrict__ st)
{
    constexpr int RG = 256 / C;
    const int c  = threadIdx.x % C;
    const int rg = threadIdx.x / C;
    float s = 0.f, s2 = 0.f;
    for (int r = blockIdx.x * RG + rg; r < n; r += gridDim.x * RG) {
        float v = in[(size_t)r * C + c];
        s += v;
        s2 = fmaf(v, v, s2);
    }
    __shared__ float ls[256], ls2[256];
    ls[threadIdx.x] = s; ls2[threadIdx.x] = s2;
    __syncthreads();
    if (rg == 0) {
#pragma unroll
        for (int g = 1; g < RG; g++) { s += ls[g * C + c]; s2 += ls2[g * C + c]; }
        atomicAdd(&st[c], (double)s);
        atomicAdd(&st[C + c], (double)s2);
    }
}

// merged pair of 256-ch colstats (out & xs)
__global__ void colstats2_kernel(const float* __restrict__ s0arr, const float* __restrict__ s1arr,
                                 int n, double* __restrict__ st0, double* __restrict__ st1)
{
    const float* in = blockIdx.y ? s1arr : s0arr;
    double* st = blockIdx.y ? st1 : st0;
    const int c = threadIdx.x;
    float s = 0.f, s2 = 0.f;
    for (int r = blockIdx.x; r < n; r += gridDim.x) {
        float v = in[(size_t)r * 256 + c];
        s += v;
        s2 = fmaf(v, v, s2);
    }
    atomicAdd(&st[c], (double)s);
    atomicAdd(&st[256 + c], (double)s2);
}

// ------------- stats of enc linear output (recomputed from rel) ------------
template<int CH>
__global__ void enc_stats_kernel(const float* __restrict__ rel, const float* __restrict__ ew,
                                 const float* __restrict__ eb, int E, double* __restrict__ st)
{
    constexpr int RG = 256 / CH;
    const int c  = threadIdx.x % CH;
    const int rg = threadIdx.x / CH;
    float wv[8];
#pragma unroll
    for (int j = 0; j < 8; j++) wv[j] = ew[j * CH + c];
    const float bv = eb[c];
    float s = 0.f, s2 = 0.f;
    for (int e = blockIdx.x * RG + rg; e < E; e += gridDim.x * RG) {
        float t = bv;
#pragma unroll
        for (int j = 0; j < 8; j++) t = fmaf(rel[(size_t)e * 8 + j], wv[j], t);
        s += t;
        s2 = fmaf(t, t, s2);
    }
    __shared__ float ls[256], ls2[256];
    ls[threadIdx.x] = s; ls2[threadIdx.x] = s2;
    __syncthreads();
    if (rg == 0) {
#pragma unroll
        for (int g = 1; g < RG; g++) { s += ls[g * CH + c]; s2 += ls2[g * CH + c]; }
        atomicAdd(&st[c], (double)s);
        atomicAdd(&st[CH + c], (double)s2);
    }
}

// ------------- finalize BN: (sum,sumsq) -> affine a,c ----------------------
__global__ void finalize_bn_kernel(const double* __restrict__ st, const float* __restrict__ g,
                                   const float* __restrict__ bt, int C, float n,
                                   float* __restrict__ ac)
{
    int c = threadIdx.x;
    if (c < C) {
        double m = st[c] / (double)n;
        double v = st[C + c] / (double)n - m * m;
        float rstd = (float)(1.0 / sqrt(v + 1e-6));
        float a = rstd * g[c];
        ac[c] = a;
        ac[C + c] = fmaf(-(float)m, a, bt[c]);
    }
}

__global__ void finalize2_kernel(const double* st0, const float* g0, const float* bt0, float* ac0,
                                 const double* st1, const float* g1, const float* bt1, float* ac1,
                                 float n)
{
    const double* st = blockIdx.x ? st1 : st0;
    const float* g  = blockIdx.x ? g1 : g0;
    const float* bt = blockIdx.x ? bt1 : bt0;
    float* ac = blockIdx.x ? ac1 : ac0;
    int c = threadIdx.x;
    double m = st[c] / (double)n;
    double v = st[256 + c] / (double)n - m * m;
    float rstd = (float)(1.0 / sqrt(v + 1e-6));
    float a = rstd * g[c];
    ac[c] = a;
    ac[256 + c] = fmaf(-(float)m, a, bt[c]);
}

// ------------- darboux edge features [E,8] ---------------------------------
__global__ void edge_rel_kernel(const int* __restrict__ src, const float* __restrict__ pos,
                                const float* __restrict__ nrm, float* __restrict__ rel, int E)
{
    int e = blockIdx.x * blockDim.x + threadIdx.x;
    if (e >= E) return;
    const int d = e >> 4;
    const int s = src[e];
    const float pix = pos[3 * d], piy = pos[3 * d + 1], piz = pos[3 * d + 2];
    const float pjx = pos[3 * s], pjy = pos[3 * s + 1], pjz = pos[3 * s + 2];
    const float nix = nrm[3 * d], niy = nrm[3 * d + 1], niz = nrm[3 * d + 2];
    const float njx = nrm[3 * s], njy = nrm[3 * s + 1], njz = nrm[3 * s + 2];
    const float dx = pjx - pix, dy = pjy - piy, dz = pjz - piz;
    const float dist = sqrtf(dx * dx + dy * dy + dz * dz);
    const float lni = sqrtf(nix * nix + niy * niy + niz * niz);
    const float lnj = sqrtf(njx * njx + njy * njy + njz * njz);
    const float uqx = dy * niz - dz * niy, uqy = dz * nix - dx * niz, uqz = dx * niy - dy * nix;
    const float vqx = uqy * niz - uqz * niy, vqy = uqz * nix - uqx * niz, vqz = uqx * niy - uqy * nix;
    const float ukx = dy * njz - dz * njy, uky = dz * njx - dx * njz, ukz = dx * njy - dy * njx;
    const float vkx = uky * njz - ukz * njy, vky = ukz * njx - ukx * njz, vkz = ukx * njy - uky * njx;
    const float luq = sqrtf(uqx * uqx + uqy * uqy + uqz * uqz);
    const float lvq = sqrtf(vqx * vqx + vqy * vqy + vqz * vqz);
    const float luk = sqrtf(ukx * ukx + uky * uky + ukz * ukz);
    const float lvk = sqrtf(vkx * vkx + vky * vky + vkz * vkz);
    const float eps = 1e-10f;
    float* r = rel + (size_t)e * 8;
    r[0] = dist;
    r[1] = (dx * nix + dy * niy + dz * niz) / (dist * lni + eps);
    r[2] = (dx * njx + dy * njy + dz * njz) / (dist * lnj + eps);
    r[3] = (nix * njx + niy * njy + niz * njz) / (lni * lnj + eps);
    r[4] = (uqx * ukx + uqy * uky + uqz * ukz) / (luq * luk + eps);
    r[5] = (vqx * vkx + vqy * vky + vqz * vkz) / (lvq * lvk + eps);
    r[6] = (uqx * vkx + uqy * vky + uqz * vkz) / (luq * lvk + eps);
    r[7] = (vqx * ukx + vqy * uky + vqz * ukz) / (lvq * luk + eps);
}

// ---------------------------------------------------------------------------
// Batched LFA: block = 256 thr, NODES = 1024/C nodes per block, 3 syncs.
// hprev is raw (pre-BN); haff = BN affine (a[HC], c[HC]) applied + lrelu on load.
// ---------------------------------------------------------------------------
template<int C>
__global__ __launch_bounds__(256)
void lfa2_kernel(const float* __restrict__ hprev, const float* __restrict__ haff,
                 const float* __restrict__ rel, const int* __restrict__ src,
                 const float* __restrict__ ew, const float* __restrict__ eb,
                 const float* __restrict__ encac,
                 const short* __restrict__ attp, const short* __restrict__ postp,
                 const float* __restrict__ postb,
                 float* __restrict__ out, int n)
{
    constexpr int HC = C / 2, NT = C / 16, NTW = NT / 4, KK = C / 32, ROWB = 2 * C;
    constexpr int NODES = 1024 / C;
    constexpr int ROWS = NODES * 16;
    constexpr int TPR = 256 / ROWS;   // threads per row in build phase

    __shared__ __align__(16) char lfS[ROWS * ROWB];
    __shared__ __align__(16) char aggS[16 * ROWB];
    __shared__ float ewS[10 * HC];

    const int tid = threadIdx.x;
    const int lane = tid & 63, w = tid >> 6, grp = (tid >> 4) & 3, l15 = tid & 15;
    const int node0 = blockIdx.x * NODES;
    const int e0g = node0 * 16;
    const int Etot = n * 16;

    // stage enc weights + fused affine into LDS
    for (int i = tid; i < 8 * HC; i += 256) ewS[i] = ew[i];
    for (int i = tid; i < HC; i += 256) {
        float a = encac[i];
        ewS[8 * HC + i] = a;
        ewS[9 * HC + i] = fmaf(a, eb[i], encac[HC + i]);
    }

    // att B fragments
    short8 Batt[NTW][KK];
#pragma unroll
    for (int t = 0; t < NTW; t++) {
        const int nt = w * NTW + t;
#pragma unroll
        for (int kk = 0; kk < KK; kk++)
            Batt[t][kk] = *reinterpret_cast<const short8*>(attp + (size_t)(((nt * KK + kk) * 4 + grp) * 16 + l15) * 8);
    }

    // ---- phase 1: build lf (gather-half + enc-half), bf16 swizzled --------
    {
        const int r = tid / TPR;
        const int p = tid % TPR;
        const int chbase = p * 32;
        const int eg = e0g + r;
        if (eg < Etot) {
            const int s = src[eg];
            const float* hrow = hprev + (size_t)s * HC + chbase;
            const float* arow = haff + chbase;
            const float* crow = haff + HC + chbase;
#pragma unroll
            for (int u = 0; u < 4; u++) {
                float4 h0 = *reinterpret_cast<const float4*>(hrow + u * 8);
                float4 h1 = *reinterpret_cast<const float4*>(hrow + u * 8 + 4);
                float4 a0 = *reinterpret_cast<const float4*>(arow + u * 8);
                float4 a1 = *reinterpret_cast<const float4*>(arow + u * 8 + 4);
                float4 c0 = *reinterpret_cast<const float4*>(crow + u * 8);
                float4 c1 = *reinterpret_cast<const float4*>(crow + u * 8 + 4);
                uint4 pk;
                pk.x = pack2bf(lrelu_f(fmaf(h0.x, a0.x, c0.x)), lrelu_f(fmaf(h0.y, a0.y, c0.y)));
                pk.y = pack2bf(lrelu_f(fmaf(h0.z, a0.z, c0.z)), lrelu_f(fmaf(h0.w, a0.w, c0.w)));
                pk.z = pack2bf(lrelu_f(fmaf(h1.x, a1.x, c1.x)), lrelu_f(fmaf(h1.y, a1.y, c1.y)));
                pk.w = pack2bf(lrelu_f(fmaf(h1.z, a1.z, c1.z)), lrelu_f(fmaf(h1.w, a1.w, c1.w)));
                const int unit = (chbase >> 3) + u;
                *reinterpret_cast<uint4*>(lfS + r * ROWB + ((unit ^ (r & 7)) << 4)) = pk;
            }
            // enc half (f32 compute)
            const float* rrow = rel + (size_t)eg * 8;
            float4 r0 = *reinterpret_cast<const float4*>(rrow);
            float4 r1 = *reinterpret_cast<const float4*>(rrow + 4);
            float rv[8] = {r0.x, r0.y, r0.z, r0.w, r1.x, r1.y, r1.z, r1.w};
#pragma unroll
            for (int u = 0; u < 4; u++) {
                float tv[8];
#pragma unroll
                for (int i2 = 0; i2 < 8; i2++) {
                    const int ch = chbase + u * 8 + i2;
                    float t = 0.f;
#pragma unroll
                    for (int j = 0; j < 8; j++) t = fmaf(rv[j], ewS[j * HC + ch], t);
                    t = fmaf(t, ewS[8 * HC + ch], ewS[9 * HC + ch]);
                    tv[i2] = lrelu_f(t);
                }
                uint4 pk;
                pk.x = pack2bf(tv[0], tv[1]); pk.y = pack2bf(tv[2], tv[3]);
                pk.z = pack2bf(tv[4], tv[5]); pk.w = pack2bf(tv[6], tv[7]);
                const int unit = ((HC + chbase) >> 3) + u;
                *reinterpret_cast<uint4*>(lfS + r * ROWB + ((unit ^ (r & 7)) << 4)) = pk;
            }
        }
    }
    __syncthreads();

    // ---- phase 2: att GEMM + segment softmax + agg ------------------------
    for (int mt = 0; mt < NODES; ++mt) {
        short8 a[KK];
        const int arow = mt * 16 + l15;
#pragma unroll
        for (int kk = 0; kk < KK; kk++)
            a[kk] = *reinterpret_cast<const short8*>(lfS + arow * ROWB + ((((kk << 2) + grp) ^ (arow & 7)) << 4));
        floatx4 acc[NTW];
#pragma unroll
        for (int t = 0; t < NTW; t++) acc[t] = (floatx4){0.f, 0.f, 0.f, 0.f};
#pragma unroll
        for (int kk = 0; kk < KK; kk++)
#pragma unroll
            for (int t = 0; t < NTW; t++)
                acc[t] = __builtin_amdgcn_mfma_f32_16x16x32_bf16(a[kk], Batt[t][kk], acc[t], 0, 0, 0);

#pragma unroll
        for (int t = 0; t < NTW; t++) {
            float m = fmaxf(fmaxf(acc[t][0], acc[t][1]), fmaxf(acc[t][2], acc[t][3]));
            m = fmaxf(m, __shfl_xor(m, 16));
            m = fmaxf(m, __shfl_xor(m, 32));
            float ev[4], ss = 0.f;
#pragma unroll
            for (int r = 0; r < 4; r++) { ev[r] = __expf(acc[t][r] - m); ss += ev[r]; }
            ss += __shfl_xor(ss, 16);
            ss += __shfl_xor(ss, 32);
            const float inv = 1.f / (ss + 1e-16f);
            const int c = (w * NTW + t) * 16 + l15;
            const int cu = c >> 3, sub = (c & 7) * 2;
            float av = 0.f;
#pragma unroll
            for (int r = 0; r < 4; r++) {
                const int krow = mt * 16 + grp * 4 + r;
                float lv = bf2f(*reinterpret_cast<const ushort*>(lfS + krow * ROWB + ((cu ^ (krow & 7)) << 4) + sub));
                av = fmaf(ev[r] * inv, lv, av);
            }
            av += __shfl_xor(av, 16);
            av += __shfl_xor(av, 32);
            if (lane < 16)
                *reinterpret_cast<ushort*>(aggS + mt * ROWB + ((cu ^ (mt & 7)) << 4) + sub) = f2bf(av);
        }
    }
    __syncthreads();

    // ---- phase 3: post GEMM ----------------------------------------------
    short8 Bpost[NTW][KK]; float pb[NTW];
#pragma unroll
    for (int t = 0; t < NTW; t++) {
        const int nt = w * NTW + t;
        pb[t] = postb[nt * 16 + l15];
#pragma unroll
        for (int kk = 0; kk < KK; kk++)
            Bpost[t][kk] = *reinterpret_cast<const short8*>(postp + (size_t)(((nt * KK + kk) * 4 + grp) * 16 + l15) * 8);
    }
    short8 a[KK];
#pragma unroll
    for (int kk = 0; kk < KK; kk++)
        a[kk] = *reinterpret_cast<const short8*>(aggS + l15 * ROWB + ((((kk << 2) + grp) ^ (l15 & 7)) << 4));
    floatx4 accP[NTW];
#pragma unroll
    for (int t = 0; t < NTW; t++) accP[t] = (floatx4){0.f, 0.f, 0.f, 0.f};
#pragma unroll
    for (int kk = 0; kk < KK; kk++)
#pragma unroll
        for (int t = 0; t < NTW; t++)
            accP[t] = __builtin_amdgcn_mfma_f32_16x16x32_bf16(a[kk], Bpost[t][kk], accP[t], 0, 0, 0);
#pragma unroll
    for (int t = 0; t < NTW; t++) {
        const int c = (w * NTW + t) * 16 + l15;
#pragma unroll
        for (int r = 0; r < 4; r++) {
            const int nb = grp * 4 + r;
            if (nb < NODES && node0 + nb < n)
                out[(size_t)(node0 + nb) * C + c] = accP[t][r] + pb[t];
        }
    }
}

// ------------- final: out = lrelu(BN(mlp2) + BN(shortcut)), in-place -------
__global__ void final_kernel(float* __restrict__ h2, const float* __restrict__ xs,
                             const float* __restrict__ ac2, const float* __restrict__ acs,
                             size_t total)
{
    size_t i = (size_t)blockIdx.x * blockDim.x + threadIdx.x;
    size_t stride = (size_t)gridDim.x * blockDim.x;
    for (; i < total; i += stride) {
        int c = (int)i & 255;
        float v = fmaf(h2[i], ac2[c], ac2[256 + c]) + fmaf(xs[i], acs[c], acs[256 + c]);
        h2[i] = lrelu_f(v);
    }
}

// ---------------------------------------------------------------------------
extern "C" void kernel_launch(void* const* d_in, const int* in_sizes, int n_in,
                              void* d_out, int out_size, void* d_ws, size_t ws_size,
                              hipStream_t stream)
{
    const float* x       = (const float*)d_in[0];
    const float* pos     = (const float*)d_in[1];
    const float* normals = (const float*)d_in[3];
    const int*   eidx    = (const int*)d_in[4];

    const float* mlp1_w = (const float*)d_in[5];
    const float* mlp1_b = (const float*)d_in[6];
    const float* mlp1_g = (const float*)d_in[7];
    const float* mlp1_bt= (const float*)d_in[8];
    const float* sc_w   = (const float*)d_in[9];
    const float* sc_b   = (const float*)d_in[10];
    const float* sc_g   = (const float*)d_in[11];
    const float* sc_bt  = (const float*)d_in[12];
    const float* mlp2_w = (const float*)d_in[13];
    const float* mlp2_b = (const float*)d_in[14];
    const float* mlp2_g = (const float*)d_in[15];
    const float* mlp2_bt= (const float*)d_in[16];
    const float* enc1_w = (const float*)d_in[17];
    const float* enc1_b = (const float*)d_in[18];
    const float* enc1_g = (const float*)d_in[19];
    const float* enc1_bt= (const float*)d_in[20];
    const float* att1_w = (const float*)d_in[21];
    const float* post1_w = (const float*)d_in[22];
    const float* post1_b = (const float*)d_in[23];
    const float* post1_g = (const float*)d_in[24];
    const float* post1_bt= (const float*)d_in[25];
    const float* enc2_w = (const float*)d_in[26];
    const float* enc2_b = (const float*)d_in[27];
    const float* enc2_g = (const float*)d_in[28];
    const float* enc2_bt= (const float*)d_in[29];
    const float* att2_w = (const float*)d_in[30];
    const float* post2_w = (const float*)d_in[31];
    const float* post2_b = (const float*)d_in[32];
    const float* post2_g = (const float*)d_in[33];
    const float* post2_bt= (const float*)d_in[34];

    float* out = (float*)d_out;

    const int n = in_sizes[0] / 128;     // 50000
    const int E = in_sizes[4] / 2;       // 800000
    const int* srcArr = eidx;

    // ---- workspace layout ----
    char* base = (char*)d_ws;
    double* stats  = (double*)base;                       // 32 KB
    float*  affine = (float*)(base + 32768);              // 16 KB
    short*  wprep  = (short*)(base + 49152);              // 212992 B
    float*  rel = (float*)(base + 262144);                // E*8
    float*  xs  = rel + (size_t)E * 8;                    // n*256
    float*  h1  = xs  + (size_t)n * 256;                  // n*32
    float*  hA  = h1  + (size_t)n * 32;                   // n*64
    float*  hB  = hA  + (size_t)n * 64;                   // n*128

    // prepped weight offsets (shorts)
    short* att1p = wprep;            // 512 frags
    short* post1p = wprep + 4096;
    short* att2p = wprep + 8192;     // 2048 frags
    short* post2p = wprep + 24576;
    short* scp   = wprep + 40960;    // 4096 frags
    short* mlp2p = wprep + 73728;

    const int OF_MLP1 = 0, OF_ENC1 = 64, OF_POST1 = 128, OF_ENC2 = 256,
              OF_POST2 = 384, OF_SC = 640, OF_MLP2 = 1152;

    hipMemsetAsync(stats, 0, 32768, stream);

    // weight prep (6 matrices, one launch)
    PrepArgs pa;
    pa.seg[0] = {att1_w,  att1p,  512,  64,  2};
    pa.seg[1] = {post1_w, post1p, 512,  64,  2};
    pa.seg[2] = {att2_w,  att2p,  2048, 128, 4};
    pa.seg[3] = {post2_w, post2p, 2048, 128, 4};
    pa.seg[4] = {sc_w,    scp,    4096, 256, 4};
    pa.seg[5] = {mlp2_w,  mlp2p,  4096, 256, 4};
    wprep_kernel<<<52, 256, 0, stream>>>(pa);

    // mlp1 (f32), shortcut (MFMA)
    lin_kernel<128, 32, 8><<<(n + 63) / 64, 256, 0, stream>>>(x, mlp1_w, mlp1_b, h1, n);
    lin_mfma_kernel<false><<<(n + 63) / 64, 256, 0, stream>>>(x, nullptr, scp, sc_b, xs, n);

    // darboux features
    edge_rel_kernel<<<(E + 255) / 256, 256, 0, stream>>>(srcArr, pos, normals, rel, E);

    // mlp1 BN stats
    colstats_kernel<32><<<512, 256, 0, stream>>>(h1, n, stats + OF_MLP1);
    finalize_bn_kernel<<<1, 256, 0, stream>>>(stats + OF_MLP1, mlp1_g, mlp1_bt, 32, (float)n, affine + OF_MLP1);

    // enc1 BN stats
    enc_stats_kernel<32><<<1024, 256, 0, stream>>>(rel, enc1_w, enc1_b, E, stats + OF_ENC1);
    finalize_bn_kernel<<<1, 256, 0, stream>>>(stats + OF_ENC1, enc1_g, enc1_bt, 32, (float)E, affine + OF_ENC1);

    // LFA 1 (C=64): h1 raw + mlp1 affine fused on gather
    lfa2_kernel<64><<<(n + 15) / 16, 256, 0, stream>>>(h1, affine + OF_MLP1, rel, srcArr,
        enc1_w, enc1_b, affine + OF_ENC1, att1p, post1p, post1_b, hA, n);
    colstats_kernel<64><<<512, 256, 0, stream>>>(hA, n, stats + OF_POST1);
    finalize_bn_kernel<<<1, 256, 0, stream>>>(stats + OF_POST1, post1_g, post1_bt, 64, (float)n, affine + OF_POST1);

    // enc2 BN stats
    enc_stats_kernel<64><<<1024, 256, 0, stream>>>(rel, enc2_w, enc2_b, E, stats + OF_ENC2);
    finalize_bn_kernel<<<1, 256, 0, stream>>>(stats + OF_ENC2, enc2_g, enc2_bt, 64, (float)E, affine + OF_ENC2);

    // LFA 2 (C=128): hA raw + post1 affine fused on gather
    lfa2_kernel<128><<<(n + 7) / 8, 256, 0, stream>>>(hA, affine + OF_POST1, rel, srcArr,
        enc2_w, enc2_b, affine + OF_ENC2, att2p, post2p, post2_b, hB, n);
    colstats_kernel<128><<<512, 256, 0, stream>>>(hB, n, stats + OF_POST2);
    finalize_bn_kernel<<<1, 256, 0, stream>>>(stats + OF_POST2, post2_g, post2_bt, 128, (float)n, affine + OF_POST2);

    // mlp2 (MFMA, post2 affine fused on load) -> d_out (pre-BN)
    lin_mfma_kernel<true><<<(n + 63) / 64, 256, 0, stream>>>(hB, affine + OF_POST2, mlp2p, mlp2_b, out, n);

    // tail BN stats (merged) + finalize (merged)
    colstats2_kernel<<<dim3(512, 2), 256, 0, stream>>>(out, xs, n, stats + OF_MLP2, stats + OF_SC);
    finalize2_kernel<<<2, 256, 0, stream>>>(stats + OF_MLP2, mlp2_g, mlp2_bt, affine + OF_MLP2,
                                            stats + OF_SC, sc_g, sc_bt, affine + OF_SC, (float)n);

    // final combine (in-place on d_out)
    final_kernel<<<4096, 256, 0, stream>>>(out, xs, affine + OF_MLP2, affine + OF_SC, (size_t)n * 256);
}

// Round 4
// 478.458 us; speedup vs baseline: 2.8287x; 1.0684x over previous
//
#include <hip/hip_runtime.h>
#include <hip/hip_bf16.h>
#include <math.h>

// ---------------------------------------------------------------------------
// DilatedResidualBlock round 4: pre-normalized bf16 gathers, identity-B MFMA
// agg, producer-fused BN stats, merged finalizes.
// N=50000, K=16 (dst = e>>4 contiguous), D_IN=128, D_OUT=256, C1=64, C2=128.
// ---------------------------------------------------------------------------

typedef __attribute__((ext_vector_type(8))) short short8;
typedef __attribute__((ext_vector_type(4))) float floatx4;

__device__ __forceinline__ float lrelu_f(float v) { return v >= 0.f ? v : 0.2f * v; }

__device__ __forceinline__ unsigned short f2bf(float f) {
    union { __hip_bfloat16 h; unsigned short u; } cv;
    cv.h = __float2bfloat16(f);
    return cv.u;
}
__device__ __forceinline__ uint pack2bf(float lo, float hi) {
    return (uint)f2bf(lo) | ((uint)f2bf(hi) << 16);
}

// ---------------- weight prep: f32 [K][Cout] -> bf16 MFMA-fragment order ----
struct PrepSeg { const float* src; short* dst; int cnt; int Cout; int KK; };
struct PrepArgs { PrepSeg seg[6]; };

__global__ void wprep_kernel(PrepArgs pa)
{
    int gid = blockIdx.x * 256 + threadIdx.x;
    int base = 0;
    for (int s = 0; s < 6; s++) {
        int c = pa.seg[s].cnt;
        if (gid < base + c) {
            int fi = gid - base;
            const float* w = pa.seg[s].src;
            const int Cout = pa.seg[s].Cout, KK = pa.seg[s].KK;
            const int l15 = fi & 15, g = (fi >> 4) & 3, rest = fi >> 6;
            const int kk = rest % KK, nt = rest / KK;
            const int col = nt * 16 + l15;
            short8 v;
#pragma unroll
            for (int e = 0; e < 8; e++)
                v[e] = (short)f2bf(w[(size_t)(kk * 32 + g * 8 + e) * Cout + col]);
            *reinterpret_cast<short8*>(pa.seg[s].dst + (size_t)fi * 8) = v;
            return;
        }
        base += c;
    }
}

// ---------------- f32 linear with fused stats (mlp1, DOUT=32) --------------
template<int DIN, int DOUT, int TM>
__global__ void lin_stats_kernel(const float* __restrict__ in, const float* __restrict__ w,
                                 const float* __restrict__ b, float* __restrict__ out,
                                 double* __restrict__ st, int n)
{
    constexpr int CT = DOUT;
    constexpr int RG = 256 / CT;
    constexpr int ROWS = TM * RG;
    __shared__ float xtile[ROWS][DIN];
    const int row0 = blockIdx.x * ROWS;
    for (int idx = threadIdx.x; idx < ROWS * DIN; idx += 256) {
        int r = idx / DIN, j = idx - r * DIN;
        int rr = row0 + r;
        xtile[r][j] = (rr < n) ? in[(size_t)rr * DIN + j] : 0.f;
    }
    __syncthreads();
    const int c  = threadIdx.x % CT;
    const int rg = threadIdx.x / CT;
    float acc[TM];
    const float bv = b[c];
#pragma unroll
    for (int t = 0; t < TM; t++) acc[t] = bv;
    for (int j = 0; j < DIN; j++) {
        float wv = w[(size_t)j * DOUT + c];
#pragma unroll
        for (int t = 0; t < TM; t++) acc[t] = fmaf(xtile[rg * TM + t][j], wv, acc[t]);
    }
    float s = 0.f, s2 = 0.f;
#pragma unroll
    for (int t = 0; t < TM; t++) {
        int rr = row0 + rg * TM + t;
        if (rr < n) {
            out[(size_t)rr * DOUT + c] = acc[t];
            s += acc[t];
            s2 = fmaf(acc[t], acc[t], s2);
        }
    }
    __syncthreads();
    float* ls  = &xtile[0][0];
    float* ls2 = ls + 256;
    ls[threadIdx.x] = s; ls2[threadIdx.x] = s2;
    __syncthreads();
    if (rg == 0) {
#pragma unroll
        for (int g = 1; g < RG; g++) { s += ls[g * CT + c]; s2 += ls2[g * CT + c]; }
        atomicAdd(&st[c], (double)s);
        atomicAdd(&st[DOUT + c], (double)s2);
    }
}

// -------- MFMA linear [n,128]@[128,256]+b, optional input affine, fused stats
template<bool AFF>
__global__ __launch_bounds__(256)
void lin_mfma_kernel(const float* __restrict__ in, const float* __restrict__ aff,
                     const short* __restrict__ wp, const float* __restrict__ b,
                     float* __restrict__ out, double* __restrict__ st, int n)
{
    __shared__ __align__(16) char aS[64 * 256];
    const int tid = threadIdx.x;
    const int w = tid >> 6, grp = (tid >> 4) & 3, l15 = tid & 15, lane = tid & 63;
    const int row0 = blockIdx.x * 64;
    {
        const int r = tid >> 2;
        const int p = tid & 3;
        const int chbase = p * 32;
        const int gr = row0 + r;
        if (gr < n) {
            const float* hrow = in + (size_t)gr * 128 + chbase;
#pragma unroll
            for (int u = 0; u < 4; u++) {
                float4 h0 = *reinterpret_cast<const float4*>(hrow + u * 8);
                float4 h1 = *reinterpret_cast<const float4*>(hrow + u * 8 + 4);
                if constexpr (AFF) {
                    const float* ar = aff + chbase + u * 8;
                    const float* cr = aff + 128 + chbase + u * 8;
                    float4 a0 = *reinterpret_cast<const float4*>(ar);
                    float4 a1 = *reinterpret_cast<const float4*>(ar + 4);
                    float4 c0 = *reinterpret_cast<const float4*>(cr);
                    float4 c1 = *reinterpret_cast<const float4*>(cr + 4);
                    h0.x = lrelu_f(fmaf(h0.x, a0.x, c0.x)); h0.y = lrelu_f(fmaf(h0.y, a0.y, c0.y));
                    h0.z = lrelu_f(fmaf(h0.z, a0.z, c0.z)); h0.w = lrelu_f(fmaf(h0.w, a0.w, c0.w));
                    h1.x = lrelu_f(fmaf(h1.x, a1.x, c1.x)); h1.y = lrelu_f(fmaf(h1.y, a1.y, c1.y));
                    h1.z = lrelu_f(fmaf(h1.z, a1.z, c1.z)); h1.w = lrelu_f(fmaf(h1.w, a1.w, c1.w));
                }
                uint4 pk;
                pk.x = pack2bf(h0.x, h0.y); pk.y = pack2bf(h0.z, h0.w);
                pk.z = pack2bf(h1.x, h1.y); pk.w = pack2bf(h1.z, h1.w);
                const int unit = (chbase >> 3) + u;
                *reinterpret_cast<uint4*>(aS + r * 256 + ((unit ^ (r & 7)) << 4)) = pk;
            }
        }
    }
    __syncthreads();

    short8 B[4][4]; float bias[4];
#pragma unroll
    for (int t = 0; t < 4; t++) {
        const int nt = w * 4 + t;
        bias[t] = b[nt * 16 + l15];
#pragma unroll
        for (int kk = 0; kk < 4; kk++)
            B[t][kk] = *reinterpret_cast<const short8*>(wp + (size_t)(((nt * 4 + kk) * 4 + grp) * 16 + l15) * 8);
    }
    float ssum[4] = {0.f, 0.f, 0.f, 0.f}, ssq[4] = {0.f, 0.f, 0.f, 0.f};
#pragma unroll
    for (int mt = 0; mt < 4; mt++) {
        short8 a[4];
        const int arow = mt * 16 + l15;
#pragma unroll
        for (int kk = 0; kk < 4; kk++)
            a[kk] = *reinterpret_cast<const short8*>(aS + arow * 256 + ((((kk << 2) + grp) ^ (arow & 7)) << 4));
#pragma unroll
        for (int t = 0; t < 4; t++) {
            floatx4 acc = {bias[t], bias[t], bias[t], bias[t]};
#pragma unroll
            for (int kk = 0; kk < 4; kk++)
                acc = __builtin_amdgcn_mfma_f32_16x16x32_bf16(a[kk], B[t][kk], acc, 0, 0, 0);
            const int c = (w * 4 + t) * 16 + l15;
#pragma unroll
            for (int r = 0; r < 4; r++) {
                const int grow = row0 + mt * 16 + grp * 4 + r;
                if (grow < n) {
                    out[(size_t)grow * 256 + c] = acc[r];
                    ssum[t] += acc[r];
                    ssq[t] = fmaf(acc[r], acc[r], ssq[t]);
                }
            }
        }
    }
#pragma unroll
    for (int t = 0; t < 4; t++) {
        float s = ssum[t], q = ssq[t];
        s += __shfl_xor(s, 16); s += __shfl_xor(s, 32);
        q += __shfl_xor(q, 16); q += __shfl_xor(q, 32);
        if (lane < 16) {
            const int c = (w * 4 + t) * 16 + l15;
            atomicAdd(&st[c], (double)s);
            atomicAdd(&st[256 + c], (double)q);
        }
    }
}

// ------------- merged enc1+enc2 BN stats (one pass over rel) ---------------
__global__ void enc12_stats_kernel(const float* __restrict__ rel,
                                   const float* __restrict__ ew1, const float* __restrict__ eb1,
                                   const float* __restrict__ ew2, const float* __restrict__ eb2,
                                   int E, double* __restrict__ st1, double* __restrict__ st2)
{
    const int t  = threadIdx.x & 63;
    const int rg = threadIdx.x >> 6;
    const int c1 = t & 31;
    float w2v[8], w1v[8];
#pragma unroll
    for (int j = 0; j < 8; j++) { w2v[j] = ew2[j * 64 + t]; w1v[j] = ew1[j * 32 + c1]; }
    const float b2v = eb2[t], b1v = eb1[c1];
    float s1 = 0.f, q1 = 0.f, s2 = 0.f, q2 = 0.f;
    for (int e = blockIdx.x * 4 + rg; e < E; e += gridDim.x * 4) {
        const float* rr = rel + (size_t)e * 8;
        float4 r0 = *reinterpret_cast<const float4*>(rr);
        float4 r1 = *reinterpret_cast<const float4*>(rr + 4);
        float rv[8] = {r0.x, r0.y, r0.z, r0.w, r1.x, r1.y, r1.z, r1.w};
        float t2 = b2v, t1 = b1v;
#pragma unroll
        for (int j = 0; j < 8; j++) { t2 = fmaf(rv[j], w2v[j], t2); t1 = fmaf(rv[j], w1v[j], t1); }
        s2 += t2; q2 = fmaf(t2, t2, q2);
        s1 += t1; q1 = fmaf(t1, t1, q1);
    }
    __shared__ float R[4][4][64];
    R[0][rg][t] = s2; R[1][rg][t] = q2; R[2][rg][t] = s1; R[3][rg][t] = q1;
    __syncthreads();
    if (rg == 0) {
        float S2 = 0.f, Q2 = 0.f;
#pragma unroll
        for (int g = 0; g < 4; g++) { S2 += R[0][g][t]; Q2 += R[1][g][t]; }
        atomicAdd(&st2[t], (double)S2);
        atomicAdd(&st2[64 + t], (double)Q2);
        if (t < 32) {
            float S1 = 0.f, Q1 = 0.f;
#pragma unroll
            for (int g = 0; g < 4; g++) { S1 += R[2][g][t]; Q1 += R[3][g][t]; }
            atomicAdd(&st1[t], (double)S1);
            atomicAdd(&st1[32 + t], (double)Q1);
        }
    }
}

// ------------- finalize BN (multi-segment): (sum,sumsq) -> affine a,c ------
struct FinSeg { const double* st; const float* g; const float* bt; float* ac; int C; float cnt; };
struct FinArgs { FinSeg seg[3]; };

__global__ void finalize_multi_kernel(FinArgs fa)
{
    FinSeg s = fa.seg[blockIdx.x];
    int c = threadIdx.x;
    if (c < s.C) {
        double m = s.st[c] / (double)s.cnt;
        double v = s.st[s.C + c] / (double)s.cnt - m * m;
        float rstd = (float)(1.0 / sqrt(v + 1e-6));
        float a = rstd * s.g[c];
        s.ac[c] = a;
        s.ac[s.C + c] = fmaf(-(float)m, a, s.bt[c]);
    }
}

// ------------- bnconv: hbn = bf16(lrelu(h*a + c)), 8 ch/thread -------------
template<int C>
__global__ void bnconv_kernel(const float* __restrict__ h, const float* __restrict__ ac,
                              unsigned short* __restrict__ o, size_t total8)
{
    size_t i = (size_t)blockIdx.x * blockDim.x + threadIdx.x;
    size_t stride = (size_t)gridDim.x * blockDim.x;
    for (; i < total8; i += stride) {
        const size_t b = i * 8;
        const int c = (int)(b & (size_t)(C - 1));
        float4 h0 = *reinterpret_cast<const float4*>(h + b);
        float4 h1 = *reinterpret_cast<const float4*>(h + b + 4);
        float4 a0 = *reinterpret_cast<const float4*>(ac + c);
        float4 a1 = *reinterpret_cast<const float4*>(ac + c + 4);
        float4 c0 = *reinterpret_cast<const float4*>(ac + C + c);
        float4 c1 = *reinterpret_cast<const float4*>(ac + C + c + 4);
        uint4 pk;
        pk.x = pack2bf(lrelu_f(fmaf(h0.x, a0.x, c0.x)), lrelu_f(fmaf(h0.y, a0.y, c0.y)));
        pk.y = pack2bf(lrelu_f(fmaf(h0.z, a0.z, c0.z)), lrelu_f(fmaf(h0.w, a0.w, c0.w)));
        pk.z = pack2bf(lrelu_f(fmaf(h1.x, a1.x, c1.x)), lrelu_f(fmaf(h1.y, a1.y, c1.y)));
        pk.w = pack2bf(lrelu_f(fmaf(h1.z, a1.z, c1.z)), lrelu_f(fmaf(h1.w, a1.w, c1.w)));
        *reinterpret_cast<uint4*>(o + b) = pk;
    }
}

// ------------- darboux edge features [E,8] ---------------------------------
__global__ void edge_rel_kernel(const int* __restrict__ src, const float* __restrict__ pos,
                                const float* __restrict__ nrm, float* __restrict__ rel, int E)
{
    int e = blockIdx.x * blockDim.x + threadIdx.x;
    if (e >= E) return;
    const int d = e >> 4;
    const int s = src[e];
    const float pix = pos[3 * d], piy = pos[3 * d + 1], piz = pos[3 * d + 2];
    const float pjx = pos[3 * s], pjy = pos[3 * s + 1], pjz = pos[3 * s + 2];
    const float nix = nrm[3 * d], niy = nrm[3 * d + 1], niz = nrm[3 * d + 2];
    const float njx = nrm[3 * s], njy = nrm[3 * s + 1], njz = nrm[3 * s + 2];
    const float dx = pjx - pix, dy = pjy - piy, dz = pjz - piz;
    const float dist = sqrtf(dx * dx + dy * dy + dz * dz);
    const float lni = sqrtf(nix * nix + niy * niy + niz * niz);
    const float lnj = sqrtf(njx * njx + njy * njy + njz * njz);
    const float uqx = dy * niz - dz * niy, uqy = dz * nix - dx * niz, uqz = dx * niy - dy * nix;
    const float vqx = uqy * niz - uqz * niy, vqy = uqz * nix - uqx * niz, vqz = uqx * niy - uqy * nix;
    const float ukx = dy * njz - dz * njy, uky = dz * njx - dx * njz, ukz = dx * njy - dy * njx;
    const float vkx = uky * njz - ukz * njy, vky = ukz * njx - ukx * njz, vkz = ukx * njy - uky * njx;
    const float luq = sqrtf(uqx * uqx + uqy * uqy + uqz * uqz);
    const float lvq = sqrtf(vqx * vqx + vqy * vqy + vqz * vqz);
    const float luk = sqrtf(ukx * ukx + uky * uky + ukz * ukz);
    const float lvk = sqrtf(vkx * vkx + vky * vky + vkz * vkz);
    const float eps = 1e-10f;
    float* r = rel + (size_t)e * 8;
    r[0] = dist;
    r[1] = (dx * nix + dy * niy + dz * niz) / (dist * lni + eps);
    r[2] = (dx * njx + dy * njy + dz * njz) / (dist * lnj + eps);
    r[3] = (nix * njx + niy * njy + niz * njz) / (lni * lnj + eps);
    r[4] = (uqx * ukx + uqy * uky + uqz * ukz) / (luq * luk + eps);
    r[5] = (vqx * vkx + vqy * vky + vqz * vkz) / (lvq * lvk + eps);
    r[6] = (uqx * vkx + uqy * vky + uqz * vkz) / (luq * lvk + eps);
    r[7] = (vqx * ukx + vqy * uky + vqz * ukz) / (lvq * luk + eps);
}

// ---------------------------------------------------------------------------
// LFA v3: bf16 pre-normalized gather, identity-B MFMA agg, fused out-stats.
// block = 256 thr, NODES = 1024/C nodes, 4 syncs total.
// ---------------------------------------------------------------------------
template<int C>
__global__ __launch_bounds__(256)
void lfa3_kernel(const unsigned short* __restrict__ hbn,   // [n, C/2] bf16 normalized
                 const float* __restrict__ rel,            // [E, 8]
                 const int* __restrict__ src,
                 const float* __restrict__ ew, const float* __restrict__ eb,
                 const float* __restrict__ encac,
                 const short* __restrict__ attp, const short* __restrict__ postp,
                 const float* __restrict__ postb,
                 float* __restrict__ out, double* __restrict__ st, int n)
{
    constexpr int HC = C / 2, NT = C / 16, NTW = NT / 4, KK = C / 32, ROWB = 2 * C;
    constexpr int NODES = 1024 / C;
    constexpr int ROWS = NODES * 16;
    constexpr int TPR = 256 / ROWS;

    __shared__ __align__(16) char lfS[ROWS * ROWB];
    __shared__ __align__(16) char aggS[16 * ROWB];
    __shared__ float ewS[10 * HC];

    const int tid = threadIdx.x;
    const int lane = tid & 63, w = tid >> 6, grp = (tid >> 4) & 3, l15 = tid & 15;
    const int node0 = blockIdx.x * NODES;
    const int e0g = node0 * 16;
    const int Etot = n * 16;
    const int kk_sel = (w * NTW) >> 1;   // kk containing this wave's output channels

    // ---- stage enc weights + fused affine; zero unused aggS rows ----
    for (int i = tid; i < 8 * HC; i += 256) ewS[i] = ew[i];
    for (int i = tid; i < HC; i += 256) {
        float a = encac[i];
        ewS[8 * HC + i] = a;
        ewS[9 * HC + i] = fmaf(a, eb[i], encac[HC + i]);
    }
    if constexpr (NODES < 16) {
        for (int i = tid; i < (16 - NODES) * ROWB / 16; i += 256)
            reinterpret_cast<uint4*>(aggS + NODES * ROWB)[i] = (uint4){0, 0, 0, 0};
    }

    // ---- att B fragments + identity selection fragments ----
    short8 Batt[NTW][KK], Bsel[NTW];
#pragma unroll
    for (int t = 0; t < NTW; t++) {
        const int nt = w * NTW + t;
#pragma unroll
        for (int kk = 0; kk < KK; kk++)
            Batt[t][kk] = *reinterpret_cast<const short8*>(attp + (size_t)(((nt * KK + kk) * 4 + grp) * 16 + l15) * 8);
        const int ng = ((nt & 1) << 1) | (l15 >> 3);
#pragma unroll
        for (int e = 0; e < 8; e++)
            Bsel[t][e] = (grp == ng && (l15 & 7) == e) ? (short)0x3F80 : (short)0;
    }
    __syncthreads();   // ewS visible

    // ---- phase 1: build lf rows (gather bf16 copy + enc f32 compute) ------
    {
        const int r = (TPR == 1) ? tid : (tid / TPR);
        const int p = (TPR == 1) ? 0 : (tid % TPR);
        constexpr int CHT = HC / TPR;     // = 32
        const int chb = p * CHT;
        const int eg = e0g + r;
        if (eg < Etot) {
            const int s = src[eg];
            const unsigned short* hrow = hbn + (size_t)s * HC + chb;
#pragma unroll
            for (int u = 0; u < CHT / 8; u++) {
                uint4 pk = *reinterpret_cast<const uint4*>(hrow + u * 8);
                const int unit = (chb >> 3) + u;
                *reinterpret_cast<uint4*>(lfS + r * ROWB + ((unit ^ (r & 7)) << 4)) = pk;
            }
            const float* rrow = rel + (size_t)eg * 8;
            float4 r0 = *reinterpret_cast<const float4*>(rrow);
            float4 r1 = *reinterpret_cast<const float4*>(rrow + 4);
            float rv[8] = {r0.x, r0.y, r0.z, r0.w, r1.x, r1.y, r1.z, r1.w};
#pragma unroll
            for (int u = 0; u < CHT / 8; u++) {
                float tv[8];
#pragma unroll
                for (int i2 = 0; i2 < 8; i2++) {
                    const int ch = chb + u * 8 + i2;
                    float tt = 0.f;
#pragma unroll
                    for (int j = 0; j < 8; j++) tt = fmaf(rv[j], ewS[j * HC + ch], tt);
                    tt = fmaf(tt, ewS[8 * HC + ch], ewS[9 * HC + ch]);
                    tv[i2] = lrelu_f(tt);
                }
                uint4 pk;
                pk.x = pack2bf(tv[0], tv[1]); pk.y = pack2bf(tv[2], tv[3]);
                pk.z = pack2bf(tv[4], tv[5]); pk.w = pack2bf(tv[6], tv[7]);
                const int unit = ((HC + chb) >> 3) + u;
                *reinterpret_cast<uint4*>(lfS + r * ROWB + ((unit ^ (r & 7)) << 4)) = pk;
            }
        }
    }
    __syncthreads();

    // ---- phase 2: att GEMM + softmax + identity-MFMA agg ------------------
    for (int mt = 0; mt < NODES; ++mt) {
        const int arow = mt * 16 + l15;
        char* rbase = lfS + arow * ROWB;
        const int x7 = l15 & 7;          // arow & 7 == l15 & 7
        short8 a[KK];
#pragma unroll
        for (int kk = 0; kk < KK; kk++)
            a[kk] = *reinterpret_cast<const short8*>(rbase + ((((kk << 2) + grp) ^ x7) << 4));
        const short8 asel = *reinterpret_cast<const short8*>(rbase + ((((kk_sel << 2) + grp) ^ x7) << 4));
        floatx4 acc[NTW];
#pragma unroll
        for (int t = 0; t < NTW; t++) acc[t] = (floatx4){0.f, 0.f, 0.f, 0.f};
#pragma unroll
        for (int kk = 0; kk < KK; kk++)
#pragma unroll
            for (int t = 0; t < NTW; t++)
                acc[t] = __builtin_amdgcn_mfma_f32_16x16x32_bf16(a[kk], Batt[t][kk], acc[t], 0, 0, 0);

#pragma unroll
        for (int t = 0; t < NTW; t++) {
            float m = fmaxf(fmaxf(acc[t][0], acc[t][1]), fmaxf(acc[t][2], acc[t][3]));
            m = fmaxf(m, __shfl_xor(m, 16));
            m = fmaxf(m, __shfl_xor(m, 32));
            float e0 = __expf(acc[t][0] - m), e1 = __expf(acc[t][1] - m);
            float e2 = __expf(acc[t][2] - m), e3 = __expf(acc[t][3] - m);
            float ss = e0 + e1 + e2 + e3;
            ss += __shfl_xor(ss, 16);
            ss += __shfl_xor(ss, 32);
            const float inv = 1.f / (ss + 1e-16f);
            floatx4 Lc = {0.f, 0.f, 0.f, 0.f};
            Lc = __builtin_amdgcn_mfma_f32_16x16x32_bf16(asel, Bsel[t], Lc, 0, 0, 0);
            float av = fmaf(e0, Lc[0], fmaf(e1, Lc[1], fmaf(e2, Lc[2], e3 * Lc[3])));
            av += __shfl_xor(av, 16);
            av += __shfl_xor(av, 32);
            av *= inv;
            if (lane < 16) {
                const int c = (w * NTW + t) * 16 + l15;
                const int cu = c >> 3, sub = (c & 7) * 2;
                *reinterpret_cast<unsigned short*>(aggS + mt * ROWB + ((cu ^ (mt & 7)) << 4) + sub) = f2bf(av);
            }
        }
    }
    __syncthreads();

    // ---- phase 3: post GEMM + fused out stats -----------------------------
    short8 Bpost[NTW][KK]; float pb[NTW];
#pragma unroll
    for (int t = 0; t < NTW; t++) {
        const int nt = w * NTW + t;
        pb[t] = postb[nt * 16 + l15];
#pragma unroll
        for (int kk = 0; kk < KK; kk++)
            Bpost[t][kk] = *reinterpret_cast<const short8*>(postp + (size_t)(((nt * KK + kk) * 4 + grp) * 16 + l15) * 8);
    }
    short8 ag[KK];
#pragma unroll
    for (int kk = 0; kk < KK; kk++)
        ag[kk] = *reinterpret_cast<const short8*>(aggS + l15 * ROWB + ((((kk << 2) + grp) ^ (l15 & 7)) << 4));
    floatx4 accP[NTW];
#pragma unroll
    for (int t = 0; t < NTW; t++) accP[t] = (floatx4){0.f, 0.f, 0.f, 0.f};
#pragma unroll
    for (int kk = 0; kk < KK; kk++)
#pragma unroll
        for (int t = 0; t < NTW; t++)
            accP[t] = __builtin_amdgcn_mfma_f32_16x16x32_bf16(ag[kk], Bpost[t][kk], accP[t], 0, 0, 0);
#pragma unroll
    for (int t = 0; t < NTW; t++) {
        const int c = (w * NTW + t) * 16 + l15;
        float s = 0.f, q = 0.f;
#pragma unroll
        for (int r = 0; r < 4; r++) {
            const int nb = grp * 4 + r;
            if (nb < NODES && node0 + nb < n) {
                const float v = accP[t][r] + pb[t];
                out[(size_t)(node0 + nb) * C + c] = v;
                s += v;
                q = fmaf(v, v, q);
            }
        }
        s += __shfl_xor(s, 16); s += __shfl_xor(s, 32);
        q += __shfl_xor(q, 16); q += __shfl_xor(q, 32);
        if (lane < 16) {
            atomicAdd(&st[c], (double)s);
            atomicAdd(&st[C + c], (double)q);
        }
    }
}

// ------------- final: out = lrelu(BN(mlp2) + BN(shortcut)), in-place -------
__global__ void final_kernel(float* __restrict__ h2, const float* __restrict__ xs,
                             const float* __restrict__ ac2, const float* __restrict__ acs,
                             size_t total)
{
    size_t i = (size_t)blockIdx.x * blockDim.x + threadIdx.x;
    size_t stride = (size_t)gridDim.x * blockDim.x;
    for (; i < total; i += stride) {
        int c = (int)i & 255;
        float v = fmaf(h2[i], ac2[c], ac2[256 + c]) + fmaf(xs[i], acs[c], acs[256 + c]);
        h2[i] = lrelu_f(v);
    }
}

// ---------------------------------------------------------------------------
extern "C" void kernel_launch(void* const* d_in, const int* in_sizes, int n_in,
                              void* d_out, int out_size, void* d_ws, size_t ws_size,
                              hipStream_t stream)
{
    const float* x       = (const float*)d_in[0];
    const float* pos     = (const float*)d_in[1];
    const float* normals = (const float*)d_in[3];
    const int*   eidx    = (const int*)d_in[4];

    const float* mlp1_w = (const float*)d_in[5];
    const float* mlp1_b = (const float*)d_in[6];
    const float* mlp1_g = (const float*)d_in[7];
    const float* mlp1_bt= (const float*)d_in[8];
    const float* sc_w   = (const float*)d_in[9];
    const float* sc_b   = (const float*)d_in[10];
    const float* sc_g   = (const float*)d_in[11];
    const float* sc_bt  = (const float*)d_in[12];
    const float* mlp2_w = (const float*)d_in[13];
    const float* mlp2_b = (const float*)d_in[14];
    const float* mlp2_g = (const float*)d_in[15];
    const float* mlp2_bt= (const float*)d_in[16];
    const float* enc1_w = (const float*)d_in[17];
    const float* enc1_b = (const float*)d_in[18];
    const float* enc1_g = (const float*)d_in[19];
    const float* enc1_bt= (const float*)d_in[20];
    const float* att1_w = (const float*)d_in[21];
    const float* post1_w = (const float*)d_in[22];
    const float* post1_b = (const float*)d_in[23];
    const float* post1_g = (const float*)d_in[24];
    const float* post1_bt= (const float*)d_in[25];
    const float* enc2_w = (const float*)d_in[26];
    const float* enc2_b = (const float*)d_in[27];
    const float* enc2_g = (const float*)d_in[28];
    const float* enc2_bt= (const float*)d_in[29];
    const float* att2_w = (const float*)d_in[30];
    const float* post2_w = (const float*)d_in[31];
    const float* post2_b = (const float*)d_in[32];
    const float* post2_g = (const float*)d_in[33];
    const float* post2_bt= (const float*)d_in[34];

    float* out = (float*)d_out;

    const int n = in_sizes[0] / 128;     // 50000
    const int E = in_sizes[4] / 2;       // 800000
    const int* srcArr = eidx;

    // ---- workspace layout ----
    char* base = (char*)d_ws;
    double* stats  = (double*)base;                       // 32 KB
    float*  affine = (float*)(base + 32768);              // 16 KB
    short*  wprep  = (short*)(base + 49152);              // 213 KB
    float*  rel = (float*)(base + 262144);                // E*8
    float*  xs  = rel + (size_t)E * 8;                    // n*256
    float*  h1  = xs  + (size_t)n * 256;                  // n*32 (later: hAbn)
    float*  hA  = h1  + (size_t)n * 32;                   // n*64
    float*  hB  = hA  + (size_t)n * 64;                   // n*128 (early: h1bn)
    unsigned short* h1bn = (unsigned short*)hB;           // n*32 bf16, dead before hB written
    unsigned short* hAbn = (unsigned short*)h1;           // n*64 bf16, reuses h1 after consumed

    short* att1p = wprep;
    short* post1p = wprep + 4096;
    short* att2p = wprep + 8192;
    short* post2p = wprep + 24576;
    short* scp   = wprep + 40960;
    short* mlp2p = wprep + 73728;

    const int OF_MLP1 = 0, OF_ENC1 = 64, OF_POST1 = 128, OF_ENC2 = 256,
              OF_POST2 = 384, OF_SC = 640, OF_MLP2 = 1152;

    hipMemsetAsync(stats, 0, 32768, stream);

    PrepArgs pa;
    pa.seg[0] = {att1_w,  att1p,  512,  64,  2};
    pa.seg[1] = {post1_w, post1p, 512,  64,  2};
    pa.seg[2] = {att2_w,  att2p,  2048, 128, 4};
    pa.seg[3] = {post2_w, post2p, 2048, 128, 4};
    pa.seg[4] = {sc_w,    scp,    4096, 256, 4};
    pa.seg[5] = {mlp2_w,  mlp2p,  4096, 256, 4};
    wprep_kernel<<<52, 256, 0, stream>>>(pa);

    // mlp1 (f32 + stats), shortcut (MFMA + stats)
    lin_stats_kernel<128, 32, 8><<<(n + 63) / 64, 256, 0, stream>>>(x, mlp1_w, mlp1_b, h1, stats + OF_MLP1, n);
    lin_mfma_kernel<false><<<(n + 63) / 64, 256, 0, stream>>>(x, nullptr, scp, sc_b, xs, stats + OF_SC, n);

    // darboux + merged enc stats
    edge_rel_kernel<<<(E + 255) / 256, 256, 0, stream>>>(srcArr, pos, normals, rel, E);
    enc12_stats_kernel<<<1024, 256, 0, stream>>>(rel, enc1_w, enc1_b, enc2_w, enc2_b, E,
                                                 stats + OF_ENC1, stats + OF_ENC2);

    // finalize mlp1 + enc1 + enc2
    FinArgs f1;
    f1.seg[0] = {stats + OF_MLP1, mlp1_g, mlp1_bt, affine + OF_MLP1, 32, (float)n};
    f1.seg[1] = {stats + OF_ENC1, enc1_g, enc1_bt, affine + OF_ENC1, 32, (float)E};
    f1.seg[2] = {stats + OF_ENC2, enc2_g, enc2_bt, affine + OF_ENC2, 64, (float)E};
    finalize_multi_kernel<<<3, 256, 0, stream>>>(f1);

    // h1 -> bf16 normalized
    bnconv_kernel<32><<<1024, 256, 0, stream>>>(h1, affine + OF_MLP1, h1bn, (size_t)n * 32 / 8);

    // LFA 1 (C=64) + fused stats
    lfa3_kernel<64><<<(n + 15) / 16, 256, 0, stream>>>(h1bn, rel, srcArr, enc1_w, enc1_b,
        affine + OF_ENC1, att1p, post1p, post1_b, hA, stats + OF_POST1, n);
    FinArgs f2;
    f2.seg[0] = {stats + OF_POST1, post1_g, post1_bt, affine + OF_POST1, 64, (float)n};
    f2.seg[1] = f2.seg[0]; f2.seg[2] = f2.seg[0];
    finalize_multi_kernel<<<1, 256, 0, stream>>>(f2);

    // hA -> bf16 normalized (into old h1 region)
    bnconv_kernel<64><<<1024, 256, 0, stream>>>(hA, affine + OF_POST1, hAbn, (size_t)n * 64 / 8);

    // LFA 2 (C=128) + fused stats
    lfa3_kernel<128><<<(n + 7) / 8, 256, 0, stream>>>(hAbn, rel, srcArr, enc2_w, enc2_b,
        affine + OF_ENC2, att2p, post2p, post2_b, hB, stats + OF_POST2, n);
    FinArgs f3;
    f3.seg[0] = {stats + OF_POST2, post2_g, post2_bt, affine + OF_POST2, 128, (float)n};
    f3.seg[1] = f3.seg[0]; f3.seg[2] = f3.seg[0];
    finalize_multi_kernel<<<1, 256, 0, stream>>>(f3);

    // mlp2 (MFMA, post2 affine fused on load, stats fused) -> d_out
    lin_mfma_kernel<true><<<(n + 63) / 64, 256, 0, stream>>>(hB, affine + OF_POST2, mlp2p, mlp2_b,
        out, stats + OF_MLP2, n);
    FinArgs f4;
    f4.seg[0] = {stats + OF_MLP2, mlp2_g, mlp2_bt, affine + OF_MLP2, 256, (float)n};
    f4.seg[1] = {stats + OF_SC,   sc_g,   sc_bt,   affine + OF_SC,   256, (float)n};
    f4.seg[2] = f4.seg[0];
    finalize_multi_kernel<<<2, 256, 0, stream>>>(f4);

    // final combine (in-place on d_out)
    final_kernel<<<4096, 256, 0, stream>>>(out, xs, affine + OF_MLP2, affine + OF_SC, (size_t)n * 256);
}